// Round 1
// baseline (1127.164 us; speedup 1.0000x reference)
//
#include <hip/hip_runtime.h>
#include <cstddef>

// SNN forward: conv1+bn1 -> IF -> pool -> conv2+bn2 -> IF -> pool -> fc1 -> LIF
//              -> fc2 -> LIF -> fc3 -> LIF -> mean over T
// T=8, B=64.  All fp32, faithful to reference rounding order (spike thresholds
// are discrete; we keep v-update op order identical to the JAX reference).
//
// Workspace layout (bytes), total 103,350,784 (assumes ws_size >= ~104 MB):
//   [0,           51380224)  p1   [TB=512][128][14*14]  stage-1 pooled spikes
//                            -- after conv2 consumes p1, region reused for:
//                            p2 (12.85MB) | h1 (2.36MB) | s3 (2.36MB) | h2 (0.26MB)
//   [51380224,   102760448)  a2   [512][128][196]       conv2+bn2 pre-activations
//   [102760448,  103350272)  w2t  [ci=128][k=9][co=128] transposed conv2 weights
//   [103350272,  103350784)  sc2  [128]                 bn2 scale

// ---------------- prep: transpose conv2 weights, bn2 scale ----------------
__global__ __launch_bounds__(256) void prep_kernel(
    const float* __restrict__ w2, const float* __restrict__ g2,
    const float* __restrict__ v2, float* __restrict__ w2t,
    float* __restrict__ sc2)
{
    int id = blockIdx.x * 256 + threadIdx.x;
    if (id < 128) sc2[id] = g2[id] / sqrtf(v2[id] + 1e-5f);
    if (id < 128 * 128 * 9) {
        // id = co*1152 + ci*9 + k  (coalesced source read)
        int co  = id / 1152;
        int rem = id - co * 1152;
        int ci  = rem / 9;
        int k   = rem - ci * 9;
        w2t[(size_t)(ci * 9 + k) * 128 + co] = w2[id];
    }
}

// ---------- stage 1: conv1 + bn1 + 8-step IF scan + 2x2 maxpool ----------
// Input to the IF scan is the SAME y0 every step -> conv once, scan in regs.
// One thread per (b, c, ph, pw) pooled output; owns the 2x2 input group.
__global__ __launch_bounds__(256) void stage1_kernel(
    const float* __restrict__ x,  const float* __restrict__ w1,
    const float* __restrict__ g1, const float* __restrict__ b1,
    const float* __restrict__ m1, const float* __restrict__ v1,
    float* __restrict__ p1)
{
    int id = blockIdx.x * 256 + threadIdx.x;   // ((b*128+c)*196 + p), exact grid
    int p  = id % 196;
    int bc = id / 196;
    int c  = bc & 127;
    int b  = bc >> 7;
    int ph = p / 14, pw = p % 14;

    float scale = g1[c] / sqrtf(v1[c] + 1e-5f);
    float mu = m1[c], beta = b1[c];
    float wl[9];
#pragma unroll
    for (int k = 0; k < 9; ++k) wl[k] = w1[c * 9 + k];

    const float* xb = x + b * 784;
    float y[4];
#pragma unroll
    for (int i = 0; i < 4; ++i) {
        int h = 2 * ph + (i >> 1);
        int w = 2 * pw + (i & 1);
        float acc = 0.f;
#pragma unroll
        for (int kh = 0; kh < 3; ++kh) {
#pragma unroll
            for (int kw = 0; kw < 3; ++kw) {
                int hh = h + kh - 1, ww = w + kw - 1;
                if ((unsigned)hh < 28u && (unsigned)ww < 28u)
                    acc += xb[hh * 28 + ww] * wl[kh * 3 + kw];
            }
        }
        y[i] = (acc - mu) * scale + beta;   // same op order as reference BN
    }

    float v0 = 0.f, v1m = 0.f, v2m = 0.f, v3m = 0.f;
    size_t outbase = (size_t)(b * 128 + c) * 196 + p;
#pragma unroll
    for (int t = 0; t < 8; ++t) {
        float any = 0.f;
        v0 += y[0]; if (v0 >= 1.0f) { any = 1.0f; v0 = 0.0f; }
        v1m += y[1]; if (v1m >= 1.0f) { any = 1.0f; v1m = 0.0f; }
        v2m += y[2]; if (v2m >= 1.0f) { any = 1.0f; v2m = 0.0f; }
        v3m += y[3]; if (v3m >= 1.0f) { any = 1.0f; v3m = 0.0f; }
        p1[(size_t)t * (64 * 128 * 196) + outbase] = any;   // [t*64+b][c][p]
    }
}

// ---------------- conv2 + bn2 (the hot kernel, fp32 direct conv) ----------
// Block = 448 threads = (co_local 32) x (row r 14); handles one tb and 32 co.
// K-loop over 8 chunks of 16 input channels staged in LDS (16x16 halo patch).
// Per (ci,kh): 4x ds_read_b128 (32-lane broadcast) + 3 weight reads -> 42 FMA.
__global__ __launch_bounds__(448) void conv2_kernel(
    const float* __restrict__ p1,  const float* __restrict__ w2t,
    const float* __restrict__ sc2, const float* __restrict__ b2,
    const float* __restrict__ m2,  float* __restrict__ a2)
{
    __shared__ float I[16][16][16];   // [ci][row+1][col+1], 16 KB
    __shared__ float Wl[16][9][32];   // [ci][k][co_local],  18 KB
    int bx  = blockIdx.x;
    int tb  = bx >> 2;
    int cot = bx & 3;
    int tid = threadIdx.x;
    int co_l = tid & 31;
    int r    = tid >> 5;              // 0..13
    int co   = cot * 32 + co_l;

    float acc[14];
#pragma unroll
    for (int i = 0; i < 14; ++i) acc[i] = 0.f;

    const float* p1b = p1 + (size_t)tb * (128 * 196);

    for (int ci0 = 0; ci0 < 128; ci0 += 16) {
        for (int idx = tid; idx < 4096; idx += 448) {
            int ci = idx >> 8;
            int rr = (idx >> 4) & 15;
            int cc = idx & 15;
            int h = rr - 1, w = cc - 1;
            float val = 0.f;
            if ((unsigned)h < 14u && (unsigned)w < 14u)
                val = p1b[(ci0 + ci) * 196 + h * 14 + w];
            I[ci][rr][cc] = val;
        }
        for (int idx = tid; idx < 16 * 9 * 32; idx += 448) {
            int ci  = idx / 288;
            int rem = idx - ci * 288;
            int k   = rem >> 5;
            int cl  = rem & 31;
            Wl[ci][k][cl] = w2t[(size_t)((ci0 + ci) * 9 + k) * 128 + cot * 32 + cl];
        }
        __syncthreads();

        for (int ci = 0; ci < 16; ++ci) {
#pragma unroll
            for (int kh = 0; kh < 3; ++kh) {
                float iv[16];
                *(float4*)&iv[0]  = *(const float4*)&I[ci][r + kh][0];
                *(float4*)&iv[4]  = *(const float4*)&I[ci][r + kh][4];
                *(float4*)&iv[8]  = *(const float4*)&I[ci][r + kh][8];
                *(float4*)&iv[12] = *(const float4*)&I[ci][r + kh][12];
                float w0  = Wl[ci][kh * 3 + 0][co_l];
                float w1v = Wl[ci][kh * 3 + 1][co_l];
                float w2v = Wl[ci][kh * 3 + 2][co_l];
#pragma unroll
                for (int c2 = 0; c2 < 14; ++c2)
                    acc[c2] += iv[c2] * w0 + iv[c2 + 1] * w1v + iv[c2 + 2] * w2v;
            }
        }
        __syncthreads();
    }

    float sc = sc2[co], mu = m2[co], beta = b2[co];
    float* outp = a2 + ((size_t)tb * 128 + co) * 196 + r * 14;
#pragma unroll
    for (int c2 = 0; c2 < 14; ++c2)
        outp[c2] = (acc[c2] - mu) * sc + beta;
}

// -------- stage 2: 8-step IF scan over conv2 output + 2x2 maxpool --------
// Thread per (b, c, ph, pw) pooled output; owns 4 membrane states.
// Writes p2 in the fc1-ready layout [t*64+b][c*49 + ph*7 + pw].
__global__ __launch_bounds__(256) void stage2_kernel(
    const float* __restrict__ a2, float* __restrict__ p2)
{
    int id = blockIdx.x * 256 + threadIdx.x;   // (b*128+c)*49 + p, exact grid
    int p  = id % 49;
    int bc = id / 49;
    int c  = bc & 127;
    int b  = bc >> 7;
    int ph = p / 7, pw = p % 7;
    int base_sp = (2 * ph) * 14 + 2 * pw;

    float v0 = 0.f, v1 = 0.f, v2 = 0.f, v3 = 0.f;
#pragma unroll
    for (int t = 0; t < 8; ++t) {
        const float* src = a2 + ((size_t)(t * 64 + b) * 128 + c) * 196 + base_sp;
        float any = 0.f;
        float x0 = src[0], x1 = src[1], x2 = src[14], x3 = src[15];
        v0 += x0; if (v0 >= 1.0f) { any = 1.0f; v0 = 0.0f; }
        v1 += x1; if (v1 >= 1.0f) { any = 1.0f; v1 = 0.0f; }
        v2 += x2; if (v2 >= 1.0f) { any = 1.0f; v2 = 0.0f; }
        v3 += x3; if (v3 >= 1.0f) { any = 1.0f; v3 = 0.0f; }
        p2[(size_t)(t * 64 + b) * 6272 + c * 49 + p] = any;
    }
}

// ---------------- tiled fp32 GEMM: C[M,N] = A[M,K] * B[N,K]^T ----------------
// Tile 32(M) x 64(N), K-chunk 16; thread computes 2x4. M%32==N%64==K%16==0.
__global__ __launch_bounds__(256) void gemm_nt_kernel(
    const float* __restrict__ A, const float* __restrict__ Bw,
    float* __restrict__ C, int M, int N, int K)
{
    __shared__ float As[16][36];   // padded: conflict-light, rows 16B-aligned
    __shared__ float Bs[16][68];
    int m_base = blockIdx.y * 32;
    int n_base = blockIdx.x * 64;
    int tid = threadIdx.x;
    int tx = tid & 15, ty = tid >> 4;
    float acc[2][4] = {{0.f,0.f,0.f,0.f},{0.f,0.f,0.f,0.f}};

    for (int k0 = 0; k0 < K; k0 += 16) {
        if (tid < 128) {
            int m  = tid >> 2;
            int kk = (tid & 3) << 2;
            float4 av = *(const float4*)&A[(size_t)(m_base + m) * K + k0 + kk];
            As[kk + 0][m] = av.x; As[kk + 1][m] = av.y;
            As[kk + 2][m] = av.z; As[kk + 3][m] = av.w;
        }
        {
            int n  = tid >> 2;
            int kk = (tid & 3) << 2;
            float4 bv = *(const float4*)&Bw[(size_t)(n_base + n) * K + k0 + kk];
            Bs[kk + 0][n] = bv.x; Bs[kk + 1][n] = bv.y;
            Bs[kk + 2][n] = bv.z; Bs[kk + 3][n] = bv.w;
        }
        __syncthreads();
#pragma unroll
        for (int kk = 0; kk < 16; ++kk) {
            float a0 = As[kk][ty * 2 + 0];
            float a1 = As[kk][ty * 2 + 1];
            float4 bv = *(const float4*)&Bs[kk][tx * 4];
            acc[0][0] += a0 * bv.x; acc[0][1] += a0 * bv.y;
            acc[0][2] += a0 * bv.z; acc[0][3] += a0 * bv.w;
            acc[1][0] += a1 * bv.x; acc[1][1] += a1 * bv.y;
            acc[1][2] += a1 * bv.z; acc[1][3] += a1 * bv.w;
        }
        __syncthreads();
    }
#pragma unroll
    for (int i = 0; i < 2; ++i) {
        float4 r;
        r.x = acc[i][0]; r.y = acc[i][1]; r.z = acc[i][2]; r.w = acc[i][3];
        *(float4*)&C[(size_t)(m_base + ty * 2 + i) * N + n_base + tx * 4] = r;
    }
}

// ------------- LIF scan: v += (x - v)*0.5; spike at v>=1; hard reset -------
__global__ __launch_bounds__(256) void lif_kernel(
    const float* __restrict__ h, float* __restrict__ s, int F)
{
    int id = blockIdx.x * 256 + threadIdx.x;   // b*F + f, exact grid
    int f = id % F;
    int b = id / F;
    float v = 0.f;
#pragma unroll
    for (int t = 0; t < 8; ++t) {
        float x = h[(size_t)(t * 64 + b) * F + f];
        v = v + (x - v) * 0.5f;                  // exact reference op order
        s[(size_t)(t * 64 + b) * F + f] = (v >= 1.0f) ? 1.0f : 0.0f;
        if (v >= 1.0f) v = 0.0f;
    }
}

// ------- tail: LIF(h2) -> fc3 (10x128) -> LIF -> mean over T. One block/b. --
__global__ __launch_bounds__(128) void tail_kernel(
    const float* __restrict__ h2, const float* __restrict__ w3,
    float* __restrict__ out)
{
    __shared__ float st[8][128];
    __shared__ float dd[8][10];
    int b = blockIdx.x;
    int tid = threadIdx.x;
    float v = 0.f;
#pragma unroll
    for (int t = 0; t < 8; ++t) {
        float x = h2[(size_t)(t * 64 + b) * 128 + tid];
        v = v + (x - v) * 0.5f;
        st[t][tid] = (v >= 1.0f) ? 1.0f : 0.0f;
        if (v >= 1.0f) v = 0.0f;
    }
    __syncthreads();
    if (tid < 80) {
        int t = tid / 10, o = tid - (tid / 10) * 10;
        float dot = 0.f;
        for (int k = 0; k < 128; ++k) dot += st[t][k] * w3[o * 128 + k];
        dd[t][o] = dot;
    }
    __syncthreads();
    if (tid < 10) {
        float vv = 0.f, cnt = 0.f;
#pragma unroll
        for (int t = 0; t < 8; ++t) {
            float x = dd[t][tid];
            vv = vv + (x - vv) * 0.5f;
            if (vv >= 1.0f) { cnt += 1.0f; vv = 0.0f; }
        }
        out[b * 10 + tid] = cnt * 0.125f;   // /8 exact
    }
}

extern "C" void kernel_launch(void* const* d_in, const int* in_sizes, int n_in,
                              void* d_out, int out_size, void* d_ws, size_t ws_size,
                              hipStream_t stream)
{
    (void)in_sizes; (void)n_in; (void)out_size; (void)ws_size;
    const float* x    = (const float*)d_in[0];
    const float* w1   = (const float*)d_in[1];
    const float* g1   = (const float*)d_in[2];
    const float* b1   = (const float*)d_in[3];
    const float* m1   = (const float*)d_in[4];
    const float* v1   = (const float*)d_in[5];
    const float* w2   = (const float*)d_in[6];
    const float* g2   = (const float*)d_in[7];
    const float* b2   = (const float*)d_in[8];
    const float* m2   = (const float*)d_in[9];
    const float* v2   = (const float*)d_in[10];
    const float* fc1w = (const float*)d_in[11];
    const float* fc2w = (const float*)d_in[12];
    const float* fc3w = (const float*)d_in[13];
    float* out = (float*)d_out;

    char* ws = (char*)d_ws;
    float* p1  = (float*)(ws + 0);
    float* a2  = (float*)(ws + 51380224);
    float* w2t = (float*)(ws + 102760448);
    float* sc2 = (float*)(ws + 103350272);
    // region-A reuse (p1 is dead after conv2):
    float* p2 = (float*)(ws + 0);
    float* h1 = p2 + 3211264;          // 512*6272
    float* s3 = h1 + 589824;           // 512*1152
    float* h2 = s3 + 589824;           // 512*1152

    prep_kernel  <<<576,  256, 0, stream>>>(w2, g2, v2, w2t, sc2);
    stage1_kernel<<<6272, 256, 0, stream>>>(x, w1, g1, b1, m1, v1, p1);
    conv2_kernel <<<2048, 448, 0, stream>>>(p1, w2t, sc2, b2, m2, a2);
    stage2_kernel<<<1568, 256, 0, stream>>>(a2, p2);
    gemm_nt_kernel<<<dim3(1152 / 64, 512 / 32), 256, 0, stream>>>(p2, fc1w, h1, 512, 1152, 6272);
    lif_kernel   <<<288,  256, 0, stream>>>(h1, s3, 1152);
    gemm_nt_kernel<<<dim3(128 / 64, 512 / 32), 256, 0, stream>>>(s3, fc2w, h2, 512, 128, 1152);
    tail_kernel  <<<64,   128, 0, stream>>>(h2, fc3w, out);
}

// Round 2
// 698.591 us; speedup vs baseline: 1.6135x; 1.6135x over previous
//
#include <hip/hip_runtime.h>
#include <hip/hip_bf16.h>
#include <cstddef>

// SNN forward, T=8, B=64.
// conv2 is now bf16-MFMA (implicit GEMM) with an EXACT 3-way bf16 weight split:
//   w = hi + mid + lo (exact for all normal fp32), spikes are {0,1} (exact bf16),
//   fp32 MFMA accumulation -> only summation-order differences vs reference.
//
// Workspace layout (bytes):
//   [0,          25690112)  p1bf  bf16 [TB=512][14][14][ci=128]  stage-1 spikes (channel-last)
//        after conv2m: region reused for p2 | h1 | s3 | h2
//   [25690112,   77070336)  a2t   fp32 [512][196][128]           conv2+bn2 pre-acts (co-last)
//   [77070336,   77955072)  w2s   bf16 [split=3][k=9][co=128][ci=128]
//   [77955072,   77955584)  sc2   fp32 [128]

typedef __attribute__((ext_vector_type(8))) short  short8;
typedef __attribute__((ext_vector_type(4))) float  f32x4;
typedef __attribute__((ext_vector_type(8))) __bf16 bf16x8;

// ---------------- prep: 3-way bf16 split of conv2 weights, bn2 scale --------
__global__ __launch_bounds__(256) void prep2_kernel(
    const float* __restrict__ w2, const float* __restrict__ g2,
    const float* __restrict__ v2, __hip_bfloat16* __restrict__ w2s,
    float* __restrict__ sc2)
{
    int id = blockIdx.x * 256 + threadIdx.x;     // (k*128 + co)*128 + ci, grid 576
    if (id < 128) sc2[id] = g2[id] / sqrtf(v2[id] + 1e-5f);
    int ci = id & 127;
    int co = (id >> 7) & 127;
    int k  = id >> 14;                            // 0..8
    float w  = w2[(co * 128 + ci) * 9 + k];
    float hi = __bfloat162float(__float2bfloat16(w));
    float r1 = w - hi;
    float md = __bfloat162float(__float2bfloat16(r1));
    float r2 = r1 - md;                           // exactly representable in bf16
    size_t base = ((size_t)k * 128 + co) * 128 + ci;
    const size_t SPL = 9 * 128 * 128;
    w2s[0 * SPL + base] = __float2bfloat16(hi);
    w2s[1 * SPL + base] = __float2bfloat16(md);
    w2s[2 * SPL + base] = __float2bfloat16(r2);
}

// ---------- stage 1: conv1 + bn1 + 8-step IF scan + 2x2 maxpool -> bf16 -----
// One thread per (b, pooled-pos, c); writes channel-last p1bf, coalesced in c.
__global__ __launch_bounds__(256) void stage1_kernel(
    const float* __restrict__ x,  const float* __restrict__ w1,
    const float* __restrict__ g1, const float* __restrict__ b1,
    const float* __restrict__ m1, const float* __restrict__ v1,
    __hip_bfloat16* __restrict__ p1bf)
{
    int id = blockIdx.x * 256 + threadIdx.x;     // (b*196 + p)*128 + c, exact grid
    int c  = id & 127;
    int bp = id >> 7;
    int p  = bp % 196;
    int b  = bp / 196;
    int ph = p / 14, pw = p % 14;

    float scale = g1[c] / sqrtf(v1[c] + 1e-5f);
    float mu = m1[c], beta = b1[c];
    float wl[9];
#pragma unroll
    for (int k = 0; k < 9; ++k) wl[k] = w1[c * 9 + k];

    const float* xb = x + b * 784;
    float y[4];
#pragma unroll
    for (int i = 0; i < 4; ++i) {
        int h = 2 * ph + (i >> 1);
        int w = 2 * pw + (i & 1);
        float acc = 0.f;
#pragma unroll
        for (int kh = 0; kh < 3; ++kh) {
#pragma unroll
            for (int kw = 0; kw < 3; ++kw) {
                int hh = h + kh - 1, ww = w + kw - 1;
                if ((unsigned)hh < 28u && (unsigned)ww < 28u)
                    acc += xb[hh * 28 + ww] * wl[kh * 3 + kw];
            }
        }
        y[i] = (acc - mu) * scale + beta;        // same op order as reference BN
    }

    float v0 = 0.f, v1m = 0.f, v2m = 0.f, v3m = 0.f;
#pragma unroll
    for (int t = 0; t < 8; ++t) {
        float any = 0.f;
        v0  += y[0]; if (v0  >= 1.0f) { any = 1.0f; v0  = 0.0f; }
        v1m += y[1]; if (v1m >= 1.0f) { any = 1.0f; v1m = 0.0f; }
        v2m += y[2]; if (v2m >= 1.0f) { any = 1.0f; v2m = 0.0f; }
        v3m += y[3]; if (v3m >= 1.0f) { any = 1.0f; v3m = 0.0f; }
        p1bf[((size_t)(t * 64 + b) * 196 + p) * 128 + c] = __float2bfloat16(any);
    }
}

// ---------------- conv2 + bn2 via MFMA (implicit GEMM) ----------------------
// Block = 256 thr = 4 waves (wm x wn); covers (tb, 64-co half). Grid 1024.
// LDS: one 16x16(+fake row) halo patch, all 128 ci, channel-last bf16,
// octet-XOR swizzled so A-fragment ds_read_b128 is ~2-way-conflict free.
// K' = 3 splits x 9 taps x 128 ci = 3456; A-frag reused across 6 MFMAs.
__global__ __launch_bounds__(256, 2) void conv2m_kernel(
    const short* __restrict__ p1bf, const short* __restrict__ w2s,
    const float* __restrict__ sc2,  const float* __restrict__ b2,
    const float* __restrict__ m2,   float* __restrict__ a2t)
{
    __shared__ short patch[272 * 128];           // 17 rows x 16 cols x 128 ci, 69,632 B
    int bx   = blockIdx.x;
    int tb   = bx >> 1;
    int ch   = bx & 1;
    int tid  = threadIdx.x;
    int lane = tid & 63;
    int wv   = tid >> 6;
    int wm   = wv >> 1, wn = wv & 1;
    int l15  = lane & 15, lg = lane >> 4;

    const short8 z8 = {0, 0, 0, 0, 0, 0, 0, 0};
    // zero border cells once: rows {0,15,16} all cols + cols {0,15} rows 1..14
    for (int idx = tid; idx < 76 * 16; idx += 256) {
        int cell = idx >> 4, sl = idx & 15;
        int prow, pcol;
        if (cell < 48) {
            int g = cell >> 4;
            prow = (g == 0) ? 0 : ((g == 1) ? 15 : 16);
            pcol = cell & 15;
        } else {
            int e = cell - 48;
            prow = 1 + (e >> 1);
            pcol = (e & 1) ? 15 : 0;
        }
        *(short8*)&patch[(prow * 16 + pcol) * 128 + sl * 8] = z8;
    }
    // stage real cells (coalesced 16B loads), swizzled LDS writes
    const short* src = p1bf + (size_t)tb * (196 * 128);
    for (int idx = tid; idx < 196 * 16; idx += 256) {
        int pos = idx >> 4, q = idx & 15;
        short8 v = *(const short8*)&src[pos * 128 + q * 8];
        int h = pos / 14, w = pos - h * 14;
        int lpos = (h + 1) * 16 + (w + 1);
        *(short8*)&patch[lpos * 128 + (q ^ (lpos & 15)) * 8] = v;
    }
    __syncthreads();

    // per-lane A addressing: m-tile mi -> pos -> (r,c); lpos = r*16+c + (kh*16+kw)
    int abase[7];
#pragma unroll
    for (int mi = 0; mi < 7; ++mi) {
        int pos = (wm * 6 + mi) * 16 + l15;      // wm0: tiles 0..6, wm1: 6..12 (tile 6 dup)
        int r = pos / 14, c = pos - r * 14;      // fake pos>=196 -> rows 14..16 (masked)
        abase[mi] = r * 16 + c;
    }
    int co0 = ch * 64 + wn * 32;

    f32x4 acc[7][2];
#pragma unroll
    for (int mi = 0; mi < 7; ++mi) {
        acc[mi][0] = (f32x4){0.f, 0.f, 0.f, 0.f};
        acc[mi][1] = (f32x4){0.f, 0.f, 0.f, 0.f};
    }

    const size_t SPL = 9 * 128 * 128;
    for (int chunk = 0; chunk < 4; ++chunk) {
#pragma unroll
        for (int tap = 0; tap < 9; ++tap) {
            const int t16 = (tap / 3) * 16 + (tap % 3);
            short8 bfr[3][2];
#pragma unroll
            for (int s = 0; s < 3; ++s)
#pragma unroll
                for (int nt = 0; nt < 2; ++nt)
                    bfr[s][nt] = *(const short8*)&w2s[s * SPL +
                        ((size_t)tap * 128 + co0 + nt * 16 + l15) * 128 + chunk * 32 + lg * 8];
#pragma unroll
            for (int mi = 0; mi < 7; ++mi) {
                int lpos = abase[mi] + t16;
                short8 av = *(const short8*)&patch[lpos * 128 +
                                                   (((chunk * 4 + lg) ^ (lpos & 15)) * 8)];
                if (wm == 1 && mi == 6 && l15 >= 4) av = z8;   // mask fake m-lanes
                bf16x8 a = __builtin_bit_cast(bf16x8, av);
#pragma unroll
                for (int s = 0; s < 3; ++s)
#pragma unroll
                    for (int nt = 0; nt < 2; ++nt)
                        acc[mi][nt] = __builtin_amdgcn_mfma_f32_16x16x32_bf16(
                            a, __builtin_bit_cast(bf16x8, bfr[s][nt]), acc[mi][nt], 0, 0, 0);
            }
        }
    }

    // epilogue: BN fold, write a2t[tb][pos][co] (coalesced in co)
    float scv[2], mv[2], bv[2];
#pragma unroll
    for (int nt = 0; nt < 2; ++nt) {
        int co = co0 + nt * 16 + l15;
        scv[nt] = sc2[co]; mv[nt] = m2[co]; bv[nt] = b2[co];
    }
#pragma unroll
    for (int mi = 0; mi < 7; ++mi) {
        int mt = wm * 6 + mi;
#pragma unroll
        for (int nt = 0; nt < 2; ++nt) {
            int co = co0 + nt * 16 + l15;
#pragma unroll
            for (int reg = 0; reg < 4; ++reg) {
                int pos = mt * 16 + lg * 4 + reg;
                if (pos < 196)
                    a2t[((size_t)tb * 196 + pos) * 128 + co] =
                        (acc[mi][nt][reg] - mv[nt]) * scv[nt] + bv[nt];
            }
        }
    }
}

// -------- stage 2: 8-step IF scan over a2t + 2x2 maxpool -> p2 (fc1 layout) --
__global__ __launch_bounds__(256) void stage2_kernel(
    const float* __restrict__ a2t, float* __restrict__ p2)
{
    int id = blockIdx.x * 256 + threadIdx.x;     // (b*49 + p)*128 + c, exact grid
    int c  = id & 127;
    int bp = id >> 7;
    int p  = bp % 49;
    int b  = bp / 49;
    int ph = p / 7, pw = p % 7;
    int s0 = (2 * ph) * 14 + 2 * pw;

    float v0 = 0.f, v1 = 0.f, v2 = 0.f, v3 = 0.f;
#pragma unroll
    for (int t = 0; t < 8; ++t) {
        const float* base = a2t + ((size_t)(t * 64 + b) * 196) * 128 + c;
        float x0 = base[(s0) * 128],      x1 = base[(s0 + 1) * 128];
        float x2 = base[(s0 + 14) * 128], x3 = base[(s0 + 15) * 128];
        float any = 0.f;
        v0 += x0; if (v0 >= 1.0f) { any = 1.0f; v0 = 0.0f; }
        v1 += x1; if (v1 >= 1.0f) { any = 1.0f; v1 = 0.0f; }
        v2 += x2; if (v2 >= 1.0f) { any = 1.0f; v2 = 0.0f; }
        v3 += x3; if (v3 >= 1.0f) { any = 1.0f; v3 = 0.0f; }
        p2[(size_t)(t * 64 + b) * 6272 + c * 49 + p] = any;
    }
}

// ---------------- tiled fp32 GEMM: C[M,N] = A[M,K] * B[N,K]^T ----------------
__global__ __launch_bounds__(256) void gemm_nt_kernel(
    const float* __restrict__ A, const float* __restrict__ Bw,
    float* __restrict__ C, int M, int N, int K)
{
    __shared__ float As[16][36];
    __shared__ float Bs[16][68];
    int m_base = blockIdx.y * 32;
    int n_base = blockIdx.x * 64;
    int tid = threadIdx.x;
    int tx = tid & 15, ty = tid >> 4;
    float acc[2][4] = {{0.f,0.f,0.f,0.f},{0.f,0.f,0.f,0.f}};

    for (int k0 = 0; k0 < K; k0 += 16) {
        if (tid < 128) {
            int m  = tid >> 2;
            int kk = (tid & 3) << 2;
            float4 av = *(const float4*)&A[(size_t)(m_base + m) * K + k0 + kk];
            As[kk + 0][m] = av.x; As[kk + 1][m] = av.y;
            As[kk + 2][m] = av.z; As[kk + 3][m] = av.w;
        }
        {
            int n  = tid >> 2;
            int kk = (tid & 3) << 2;
            float4 bv = *(const float4*)&Bw[(size_t)(n_base + n) * K + k0 + kk];
            Bs[kk + 0][n] = bv.x; Bs[kk + 1][n] = bv.y;
            Bs[kk + 2][n] = bv.z; Bs[kk + 3][n] = bv.w;
        }
        __syncthreads();
#pragma unroll
        for (int kk = 0; kk < 16; ++kk) {
            float a0 = As[kk][ty * 2 + 0];
            float a1 = As[kk][ty * 2 + 1];
            float4 bv = *(const float4*)&Bs[kk][tx * 4];
            acc[0][0] += a0 * bv.x; acc[0][1] += a0 * bv.y;
            acc[0][2] += a0 * bv.z; acc[0][3] += a0 * bv.w;
            acc[1][0] += a1 * bv.x; acc[1][1] += a1 * bv.y;
            acc[1][2] += a1 * bv.z; acc[1][3] += a1 * bv.w;
        }
        __syncthreads();
    }
#pragma unroll
    for (int i = 0; i < 2; ++i) {
        float4 r;
        r.x = acc[i][0]; r.y = acc[i][1]; r.z = acc[i][2]; r.w = acc[i][3];
        *(float4*)&C[(size_t)(m_base + ty * 2 + i) * N + n_base + tx * 4] = r;
    }
}

// ------------- LIF scan: v += (x - v)*0.5; spike at v>=1; hard reset -------
__global__ __launch_bounds__(256) void lif_kernel(
    const float* __restrict__ h, float* __restrict__ s, int F)
{
    int id = blockIdx.x * 256 + threadIdx.x;
    int f = id % F;
    int b = id / F;
    float v = 0.f;
#pragma unroll
    for (int t = 0; t < 8; ++t) {
        float x = h[(size_t)(t * 64 + b) * F + f];
        v = v + (x - v) * 0.5f;
        s[(size_t)(t * 64 + b) * F + f] = (v >= 1.0f) ? 1.0f : 0.0f;
        if (v >= 1.0f) v = 0.0f;
    }
}

// ------- tail: LIF(h2) -> fc3 (10x128) -> LIF -> mean over T. One block/b. --
__global__ __launch_bounds__(128) void tail_kernel(
    const float* __restrict__ h2, const float* __restrict__ w3,
    float* __restrict__ out)
{
    __shared__ float st[8][128];
    __shared__ float dd[8][10];
    int b = blockIdx.x;
    int tid = threadIdx.x;
    float v = 0.f;
#pragma unroll
    for (int t = 0; t < 8; ++t) {
        float x = h2[(size_t)(t * 64 + b) * 128 + tid];
        v = v + (x - v) * 0.5f;
        st[t][tid] = (v >= 1.0f) ? 1.0f : 0.0f;
        if (v >= 1.0f) v = 0.0f;
    }
    __syncthreads();
    if (tid < 80) {
        int t = tid / 10, o = tid - (tid / 10) * 10;
        float dot = 0.f;
        for (int k = 0; k < 128; ++k) dot += st[t][k] * w3[o * 128 + k];
        dd[t][o] = dot;
    }
    __syncthreads();
    if (tid < 10) {
        float vv = 0.f, cnt = 0.f;
#pragma unroll
        for (int t = 0; t < 8; ++t) {
            float x = dd[t][tid];
            vv = vv + (x - vv) * 0.5f;
            if (vv >= 1.0f) { cnt += 1.0f; vv = 0.0f; }
        }
        out[b * 10 + tid] = cnt * 0.125f;
    }
}

extern "C" void kernel_launch(void* const* d_in, const int* in_sizes, int n_in,
                              void* d_out, int out_size, void* d_ws, size_t ws_size,
                              hipStream_t stream)
{
    (void)in_sizes; (void)n_in; (void)out_size; (void)ws_size;
    const float* x    = (const float*)d_in[0];
    const float* w1   = (const float*)d_in[1];
    const float* g1   = (const float*)d_in[2];
    const float* b1   = (const float*)d_in[3];
    const float* m1   = (const float*)d_in[4];
    const float* v1   = (const float*)d_in[5];
    const float* w2   = (const float*)d_in[6];
    const float* g2   = (const float*)d_in[7];
    const float* b2   = (const float*)d_in[8];
    const float* m2   = (const float*)d_in[9];
    const float* v2   = (const float*)d_in[10];
    const float* fc1w = (const float*)d_in[11];
    const float* fc2w = (const float*)d_in[12];
    const float* fc3w = (const float*)d_in[13];
    float* out = (float*)d_out;

    char* ws = (char*)d_ws;
    __hip_bfloat16* p1bf = (__hip_bfloat16*)(ws + 0);
    float*          a2t  = (float*)(ws + 25690112);
    __hip_bfloat16* w2s  = (__hip_bfloat16*)(ws + 77070336);
    float*          sc2  = (float*)(ws + 77955072);
    // region-0 reuse after conv2m consumes p1bf:
    float* p2 = (float*)(ws + 0);              // 512*6272
    float* h1 = p2 + 3211264;                  // 512*1152
    float* s3 = h1 + 589824;                   // 512*1152
    float* h2 = s3 + 589824;                   // 512*128

    prep2_kernel <<<576,  256, 0, stream>>>(w2, g2, v2, w2s, sc2);
    stage1_kernel<<<6272, 256, 0, stream>>>(x, w1, g1, b1, m1, v1, p1bf);
    conv2m_kernel<<<1024, 256, 0, stream>>>((const short*)p1bf, (const short*)w2s,
                                            sc2, b2, m2, a2t);
    stage2_kernel<<<1568, 256, 0, stream>>>(a2t, p2);
    gemm_nt_kernel<<<dim3(1152 / 64, 512 / 32), 256, 0, stream>>>(p2, fc1w, h1, 512, 1152, 6272);
    lif_kernel   <<<288,  256, 0, stream>>>(h1, s3, 1152);
    gemm_nt_kernel<<<dim3(128 / 64, 512 / 32), 256, 0, stream>>>(s3, fc2w, h2, 512, 128, 1152);
    tail_kernel  <<<64,   128, 0, stream>>>(h2, fc3w, out);
}

// Round 3
// 466.223 us; speedup vs baseline: 2.4177x; 1.4984x over previous
//
#include <hip/hip_runtime.h>
#include <hip/hip_bf16.h>
#include <cstddef>

// SNN forward, T=8, B=64.
// conv2 AND fc1 now run on bf16 MFMA with EXACT 3-way bf16 weight splits
// (w = hi+mid+lo exactly; spikes are {0,1}, exact in bf16; fp32 MFMA accum ->
//  only summation-order differences vs the fp32 reference).
//
// Workspace layout (bytes), high water 77,955,584:
//   [0,          25690112)  p1bf  bf16 [TB=512][196][ci=128]  stage-1 spikes
//        region reused after conv2m:
//          p2bf [0,        6422528)   bf16 [512][6272]   stage-2 spikes
//          part [6422528,  22937600)  fp32 [7][512][1152] fc1 split-K partials
//          s3   [22937600, 25296896)  fp32 [512][1152]   LIF3 spikes
//          h2   [25296896, 25559040)  fp32 [512][128]    fc2 output
//   [25690112,  77070336)  a2t   fp32 [512][196][128]    conv2+bn2 pre-acts
//        region reused after stage2:
//          w1s  [25690112, 69042176)  bf16 [3][1152][6272] fc1 weight splits
//   [77070336,  77955072)  w2s   bf16 [3][9][128][128]   conv2 weight splits
//   [77955072,  77955584)  sc2   fp32 [128]

typedef __attribute__((ext_vector_type(8))) short  short8;
typedef __attribute__((ext_vector_type(4))) float  f32x4;
typedef __attribute__((ext_vector_type(8))) __bf16 bf16x8;

__device__ inline short f2bf_bits(float x) {
    __hip_bfloat16 h = __float2bfloat16(x);
    return *reinterpret_cast<short*>(&h);
}
__device__ inline float bfbits2f(short b) {
    __hip_bfloat16 h;
    *reinterpret_cast<short*>(&h) = b;
    return __bfloat162float(h);
}

// ---------------- prep: 3-way bf16 split of conv2 weights, bn2 scale --------
__global__ __launch_bounds__(256) void prep2_kernel(
    const float* __restrict__ w2, const float* __restrict__ g2,
    const float* __restrict__ v2, __hip_bfloat16* __restrict__ w2s,
    float* __restrict__ sc2)
{
    int id = blockIdx.x * 256 + threadIdx.x;     // co*1152 + ci*9 + k? no: see below
    if (id < 128) sc2[id] = g2[id] / sqrtf(v2[id] + 1e-5f);
    int ci = id & 127;
    int co = (id >> 7) & 127;
    int k  = id >> 14;                            // 0..8
    float w  = w2[(co * 128 + ci) * 9 + k];
    float hi = __bfloat162float(__float2bfloat16(w));
    float r1 = w - hi;
    float md = __bfloat162float(__float2bfloat16(r1));
    float r2 = r1 - md;                           // exactly representable in bf16
    size_t base = ((size_t)k * 128 + co) * 128 + ci;
    const size_t SPL = 9 * 128 * 128;
    w2s[0 * SPL + base] = __float2bfloat16(hi);
    w2s[1 * SPL + base] = __float2bfloat16(md);
    w2s[2 * SPL + base] = __float2bfloat16(r2);
}

// ---------------- prep: 3-way bf16 split of fc1 weights ---------------------
// Layout: w1s[s][n][k], s-stride 1152*6272. Thread = (n, k-octet): reads 32B
// coalesced, writes 16B x3 coalesced (consecutive threads -> consecutive koct).
__global__ __launch_bounds__(256) void prep_fc1_kernel(
    const float* __restrict__ w, short* __restrict__ w1s)
{
    int id = blockIdx.x * 256 + threadIdx.x;      // n*784 + koct, grid 3528
    int koct = id % 784;
    int n    = id / 784;
    const float* src = w + (size_t)n * 6272 + koct * 8;
    float4 va = *(const float4*)src;
    float4 vb = *(const float4*)(src + 4);
    float wv[8] = {va.x, va.y, va.z, va.w, vb.x, vb.y, vb.z, vb.w};
    short8 hi8, md8, lo8;
#pragma unroll
    for (int e = 0; e < 8; ++e) {
        float x  = wv[e];
        short hb = f2bf_bits(x);
        float r1 = x - bfbits2f(hb);
        short mb = f2bf_bits(r1);
        float r2 = r1 - bfbits2f(mb);
        hi8[e] = hb; md8[e] = mb; lo8[e] = f2bf_bits(r2);
    }
    const size_t SPL = (size_t)1152 * 6272;
    size_t base = (size_t)n * 6272 + koct * 8;
    *(short8*)&w1s[0 * SPL + base] = hi8;
    *(short8*)&w1s[1 * SPL + base] = md8;
    *(short8*)&w1s[2 * SPL + base] = lo8;
}

// ---------- stage 1: conv1 + bn1 + 8-step IF scan + 2x2 maxpool -> bf16 -----
__global__ __launch_bounds__(256) void stage1_kernel(
    const float* __restrict__ x,  const float* __restrict__ w1,
    const float* __restrict__ g1, const float* __restrict__ b1,
    const float* __restrict__ m1, const float* __restrict__ v1,
    __hip_bfloat16* __restrict__ p1bf)
{
    int id = blockIdx.x * 256 + threadIdx.x;     // (b*196 + p)*128 + c, exact grid
    int c  = id & 127;
    int bp = id >> 7;
    int p  = bp % 196;
    int b  = bp / 196;
    int ph = p / 14, pw = p % 14;

    float scale = g1[c] / sqrtf(v1[c] + 1e-5f);
    float mu = m1[c], beta = b1[c];
    float wl[9];
#pragma unroll
    for (int k = 0; k < 9; ++k) wl[k] = w1[c * 9 + k];

    const float* xb = x + b * 784;
    float y[4];
#pragma unroll
    for (int i = 0; i < 4; ++i) {
        int h = 2 * ph + (i >> 1);
        int w = 2 * pw + (i & 1);
        float acc = 0.f;
#pragma unroll
        for (int kh = 0; kh < 3; ++kh) {
#pragma unroll
            for (int kw = 0; kw < 3; ++kw) {
                int hh = h + kh - 1, ww = w + kw - 1;
                if ((unsigned)hh < 28u && (unsigned)ww < 28u)
                    acc += xb[hh * 28 + ww] * wl[kh * 3 + kw];
            }
        }
        y[i] = (acc - mu) * scale + beta;        // same op order as reference BN
    }

    float v0 = 0.f, v1m = 0.f, v2m = 0.f, v3m = 0.f;
#pragma unroll
    for (int t = 0; t < 8; ++t) {
        float any = 0.f;
        v0  += y[0]; if (v0  >= 1.0f) { any = 1.0f; v0  = 0.0f; }
        v1m += y[1]; if (v1m >= 1.0f) { any = 1.0f; v1m = 0.0f; }
        v2m += y[2]; if (v2m >= 1.0f) { any = 1.0f; v2m = 0.0f; }
        v3m += y[3]; if (v3m >= 1.0f) { any = 1.0f; v3m = 0.0f; }
        p1bf[((size_t)(t * 64 + b) * 196 + p) * 128 + c] = __float2bfloat16(any);
    }
}

// ---------------- conv2 + bn2 via MFMA (implicit GEMM) ----------------------
__global__ __launch_bounds__(256, 2) void conv2m_kernel(
    const short* __restrict__ p1bf, const short* __restrict__ w2s,
    const float* __restrict__ sc2,  const float* __restrict__ b2,
    const float* __restrict__ m2,   float* __restrict__ a2t)
{
    __shared__ short patch[272 * 128];           // 17 rows x 16 cols x 128 ci
    int bx   = blockIdx.x;
    int tb   = bx >> 1;
    int ch   = bx & 1;
    int tid  = threadIdx.x;
    int lane = tid & 63;
    int wv   = tid >> 6;
    int wm   = wv >> 1, wn = wv & 1;
    int l15  = lane & 15, lg = lane >> 4;

    const short8 z8 = {0, 0, 0, 0, 0, 0, 0, 0};
    for (int idx = tid; idx < 76 * 16; idx += 256) {
        int cell = idx >> 4, sl = idx & 15;
        int prow, pcol;
        if (cell < 48) {
            int g = cell >> 4;
            prow = (g == 0) ? 0 : ((g == 1) ? 15 : 16);
            pcol = cell & 15;
        } else {
            int e = cell - 48;
            prow = 1 + (e >> 1);
            pcol = (e & 1) ? 15 : 0;
        }
        *(short8*)&patch[(prow * 16 + pcol) * 128 + sl * 8] = z8;
    }
    const short* src = p1bf + (size_t)tb * (196 * 128);
    for (int idx = tid; idx < 196 * 16; idx += 256) {
        int pos = idx >> 4, q = idx & 15;
        short8 v = *(const short8*)&src[pos * 128 + q * 8];
        int h = pos / 14, w = pos - h * 14;
        int lpos = (h + 1) * 16 + (w + 1);
        *(short8*)&patch[lpos * 128 + (q ^ (lpos & 15)) * 8] = v;
    }
    __syncthreads();

    int abase[7];
#pragma unroll
    for (int mi = 0; mi < 7; ++mi) {
        int pos = (wm * 6 + mi) * 16 + l15;
        int r = pos / 14, c = pos - r * 14;
        abase[mi] = r * 16 + c;
    }
    int co0 = ch * 64 + wn * 32;

    f32x4 acc[7][2];
#pragma unroll
    for (int mi = 0; mi < 7; ++mi) {
        acc[mi][0] = (f32x4){0.f, 0.f, 0.f, 0.f};
        acc[mi][1] = (f32x4){0.f, 0.f, 0.f, 0.f};
    }

    const size_t SPL = 9 * 128 * 128;
    for (int chunk = 0; chunk < 4; ++chunk) {
#pragma unroll
        for (int tap = 0; tap < 9; ++tap) {
            const int t16 = (tap / 3) * 16 + (tap % 3);
            short8 bfr[3][2];
#pragma unroll
            for (int s = 0; s < 3; ++s)
#pragma unroll
                for (int nt = 0; nt < 2; ++nt)
                    bfr[s][nt] = *(const short8*)&w2s[s * SPL +
                        ((size_t)tap * 128 + co0 + nt * 16 + l15) * 128 + chunk * 32 + lg * 8];
#pragma unroll
            for (int mi = 0; mi < 7; ++mi) {
                int lpos = abase[mi] + t16;
                short8 av = *(const short8*)&patch[lpos * 128 +
                                                   (((chunk * 4 + lg) ^ (lpos & 15)) * 8)];
                if (wm == 1 && mi == 6 && l15 >= 4) av = z8;
                bf16x8 a = __builtin_bit_cast(bf16x8, av);
#pragma unroll
                for (int s = 0; s < 3; ++s)
#pragma unroll
                    for (int nt = 0; nt < 2; ++nt)
                        acc[mi][nt] = __builtin_amdgcn_mfma_f32_16x16x32_bf16(
                            a, __builtin_bit_cast(bf16x8, bfr[s][nt]), acc[mi][nt], 0, 0, 0);
            }
        }
    }

    float scv[2], mv[2], bv[2];
#pragma unroll
    for (int nt = 0; nt < 2; ++nt) {
        int co = co0 + nt * 16 + l15;
        scv[nt] = sc2[co]; mv[nt] = m2[co]; bv[nt] = b2[co];
    }
#pragma unroll
    for (int mi = 0; mi < 7; ++mi) {
        int mt = wm * 6 + mi;
#pragma unroll
        for (int nt = 0; nt < 2; ++nt) {
            int co = co0 + nt * 16 + l15;
#pragma unroll
            for (int reg = 0; reg < 4; ++reg) {
                int pos = mt * 16 + lg * 4 + reg;
                if (pos < 196)
                    a2t[((size_t)tb * 196 + pos) * 128 + co] =
                        (acc[mi][nt][reg] - mv[nt]) * scv[nt] + bv[nt];
            }
        }
    }
}

// -------- stage 2: 8-step IF scan over a2t + 2x2 maxpool -> p2 bf16 ---------
__global__ __launch_bounds__(256) void stage2_kernel(
    const float* __restrict__ a2t, __hip_bfloat16* __restrict__ p2)
{
    int id = blockIdx.x * 256 + threadIdx.x;     // (b*49 + p)*128 + c, exact grid
    int c  = id & 127;
    int bp = id >> 7;
    int p  = bp % 49;
    int b  = bp / 49;
    int ph = p / 7, pw = p % 7;
    int s0 = (2 * ph) * 14 + 2 * pw;

    float v0 = 0.f, v1 = 0.f, v2 = 0.f, v3 = 0.f;
#pragma unroll
    for (int t = 0; t < 8; ++t) {
        const float* base = a2t + ((size_t)(t * 64 + b) * 196) * 128 + c;
        float x0 = base[(s0) * 128],      x1 = base[(s0 + 1) * 128];
        float x2 = base[(s0 + 14) * 128], x3 = base[(s0 + 15) * 128];
        float any = 0.f;
        v0 += x0; if (v0 >= 1.0f) { any = 1.0f; v0 = 0.0f; }
        v1 += x1; if (v1 >= 1.0f) { any = 1.0f; v1 = 0.0f; }
        v2 += x2; if (v2 >= 1.0f) { any = 1.0f; v2 = 0.0f; }
        v3 += x3; if (v3 >= 1.0f) { any = 1.0f; v3 = 0.0f; }
        p2[(size_t)(t * 64 + b) * 6272 + c * 49 + p] = __float2bfloat16(any);
    }
}

// ---------------- fc1 via MFMA, split-K=7 -----------------------------------
// Block 256 thr = 4 waves (2 wm x 2 wn); tile BM=64 x BN=128; grid (9,8,7).
// A staged in LDS (8 KB) with octet-XOR swizzle (write side pre-swizzled,
// read side applies the same XOR -> ds_read_b128 is ~2-way, free).
__global__ __launch_bounds__(256, 2) void fc1m_kernel(
    const short* __restrict__ A,     // p2 bf16 [512][6272]
    const short* __restrict__ Bsp,   // w1s bf16 [3][1152][6272]
    float* __restrict__ part)        // [7][512][1152]
{
    __shared__ short At[64 * 64];
    const int n0 = blockIdx.x * 128;
    const int m0 = blockIdx.y * 64;
    const int kz = blockIdx.z;                   // K-chunk: 14 steps of 64
    const int tid  = threadIdx.x;
    const int lane = tid & 63;
    const int wv   = tid >> 6;
    const int wm = wv >> 1, wn = wv & 1;
    const int l15 = lane & 15, lg = lane >> 4;
    const size_t SPL = (size_t)1152 * 6272;

    f32x4 acc[2][4];
#pragma unroll
    for (int mi = 0; mi < 2; ++mi)
#pragma unroll
        for (int nt = 0; nt < 4; ++nt)
            acc[mi][nt] = (f32x4){0.f, 0.f, 0.f, 0.f};

    for (int ks = 0; ks < 14; ++ks) {
        int k0 = kz * 896 + ks * 64;
        // stage A tile [64 rows][64 k] (swizzled octets)
#pragma unroll
        for (int pp = 0; pp < 2; ++pp) {
            int i = pp * 256 + tid;
            int row = i >> 3, q = i & 7;
            short8 v = *(const short8*)&A[(size_t)(m0 + row) * 6272 + k0 + ((q ^ (row & 7)) << 3)];
            *(short8*)&At[row * 64 + q * 8] = v;
        }
        __syncthreads();

#pragma unroll
        for (int kh = 0; kh < 2; ++kh) {
            bf16x8 a[2];
#pragma unroll
            for (int mi = 0; mi < 2; ++mi) {
                int r = wm * 32 + mi * 16 + l15;
                int q = (kh * 4 + lg) ^ (r & 7);
                a[mi] = __builtin_bit_cast(bf16x8, *(const short8*)&At[r * 64 + q * 8]);
            }
#pragma unroll
            for (int s = 0; s < 3; ++s) {
#pragma unroll
                for (int nt = 0; nt < 4; ++nt) {
                    bf16x8 b = __builtin_bit_cast(bf16x8, *(const short8*)&Bsp[s * SPL +
                        (size_t)(n0 + wn * 64 + nt * 16 + l15) * 6272 + k0 + kh * 32 + lg * 8]);
                    acc[0][nt] = __builtin_amdgcn_mfma_f32_16x16x32_bf16(a[0], b, acc[0][nt], 0, 0, 0);
                    acc[1][nt] = __builtin_amdgcn_mfma_f32_16x16x32_bf16(a[1], b, acc[1][nt], 0, 0, 0);
                }
            }
        }
        __syncthreads();
    }

    float* dst = part + (size_t)kz * (512 * 1152);
#pragma unroll
    for (int mi = 0; mi < 2; ++mi) {
#pragma unroll
        for (int nt = 0; nt < 4; ++nt) {
            int n = n0 + wn * 64 + nt * 16 + l15;
#pragma unroll
            for (int reg = 0; reg < 4; ++reg) {
                int m = m0 + wm * 32 + mi * 16 + lg * 4 + reg;
                dst[(size_t)m * 1152 + n] = acc[mi][nt][reg];
            }
        }
    }
}

// --------- fused: reduce 7 fc1 partials + LIF scan -> s3 (fp32 spikes) ------
__global__ __launch_bounds__(256) void lif2_kernel(
    const float* __restrict__ part, float* __restrict__ s3)
{
    int id = blockIdx.x * 256 + threadIdx.x;     // b*1152 + f, grid 288 exact
    int f = id % 1152;
    int b = id / 1152;
    const size_t S = (size_t)512 * 1152;
    float v = 0.f;
#pragma unroll
    for (int t = 0; t < 8; ++t) {
        size_t off = (size_t)(t * 64 + b) * 1152 + f;
        float x = part[off];
#pragma unroll
        for (int s = 1; s < 7; ++s) x += part[s * S + off];
        v = v + (x - v) * 0.5f;
        s3[off] = (v >= 1.0f) ? 1.0f : 0.0f;
        if (v >= 1.0f) v = 0.0f;
    }
}

// ---------------- tiled fp32 GEMM (fc2): C[M,N] = A[M,K] * B[N,K]^T ---------
__global__ __launch_bounds__(256) void gemm_nt_kernel(
    const float* __restrict__ A, const float* __restrict__ Bw,
    float* __restrict__ C, int M, int N, int K)
{
    __shared__ float As[16][36];
    __shared__ float Bs[16][68];
    int m_base = blockIdx.y * 32;
    int n_base = blockIdx.x * 64;
    int tid = threadIdx.x;
    int tx = tid & 15, ty = tid >> 4;
    float acc[2][4] = {{0.f,0.f,0.f,0.f},{0.f,0.f,0.f,0.f}};

    for (int k0 = 0; k0 < K; k0 += 16) {
        if (tid < 128) {
            int m  = tid >> 2;
            int kk = (tid & 3) << 2;
            float4 av = *(const float4*)&A[(size_t)(m_base + m) * K + k0 + kk];
            As[kk + 0][m] = av.x; As[kk + 1][m] = av.y;
            As[kk + 2][m] = av.z; As[kk + 3][m] = av.w;
        }
        {
            int n  = tid >> 2;
            int kk = (tid & 3) << 2;
            float4 bv = *(const float4*)&Bw[(size_t)(n_base + n) * K + k0 + kk];
            Bs[kk + 0][n] = bv.x; Bs[kk + 1][n] = bv.y;
            Bs[kk + 2][n] = bv.z; Bs[kk + 3][n] = bv.w;
        }
        __syncthreads();
#pragma unroll
        for (int kk = 0; kk < 16; ++kk) {
            float a0 = As[kk][ty * 2 + 0];
            float a1 = As[kk][ty * 2 + 1];
            float4 bv = *(const float4*)&Bs[kk][tx * 4];
            acc[0][0] += a0 * bv.x; acc[0][1] += a0 * bv.y;
            acc[0][2] += a0 * bv.z; acc[0][3] += a0 * bv.w;
            acc[1][0] += a1 * bv.x; acc[1][1] += a1 * bv.y;
            acc[1][2] += a1 * bv.z; acc[1][3] += a1 * bv.w;
        }
        __syncthreads();
    }
#pragma unroll
    for (int i = 0; i < 2; ++i) {
        float4 r;
        r.x = acc[i][0]; r.y = acc[i][1]; r.z = acc[i][2]; r.w = acc[i][3];
        *(float4*)&C[(size_t)(m_base + ty * 2 + i) * N + n_base + tx * 4] = r;
    }
}

// ------- tail: LIF(h2) -> fc3 (10x128) -> LIF -> mean over T. One block/b. --
__global__ __launch_bounds__(128) void tail_kernel(
    const float* __restrict__ h2, const float* __restrict__ w3,
    float* __restrict__ out)
{
    __shared__ float st[8][128];
    __shared__ float dd[8][10];
    int b = blockIdx.x;
    int tid = threadIdx.x;
    float v = 0.f;
#pragma unroll
    for (int t = 0; t < 8; ++t) {
        float x = h2[(size_t)(t * 64 + b) * 128 + tid];
        v = v + (x - v) * 0.5f;
        st[t][tid] = (v >= 1.0f) ? 1.0f : 0.0f;
        if (v >= 1.0f) v = 0.0f;
    }
    __syncthreads();
    if (tid < 80) {
        int t = tid / 10, o = tid - (tid / 10) * 10;
        float dot = 0.f;
        for (int k = 0; k < 128; ++k) dot += st[t][k] * w3[o * 128 + k];
        dd[t][o] = dot;
    }
    __syncthreads();
    if (tid < 10) {
        float vv = 0.f, cnt = 0.f;
#pragma unroll
        for (int t = 0; t < 8; ++t) {
            float x = dd[t][tid];
            vv = vv + (x - vv) * 0.5f;
            if (vv >= 1.0f) { cnt += 1.0f; vv = 0.0f; }
        }
        out[b * 10 + tid] = cnt * 0.125f;
    }
}

extern "C" void kernel_launch(void* const* d_in, const int* in_sizes, int n_in,
                              void* d_out, int out_size, void* d_ws, size_t ws_size,
                              hipStream_t stream)
{
    (void)in_sizes; (void)n_in; (void)out_size; (void)ws_size;
    const float* x    = (const float*)d_in[0];
    const float* w1   = (const float*)d_in[1];
    const float* g1   = (const float*)d_in[2];
    const float* b1   = (const float*)d_in[3];
    const float* m1   = (const float*)d_in[4];
    const float* v1   = (const float*)d_in[5];
    const float* w2   = (const float*)d_in[6];
    const float* g2   = (const float*)d_in[7];
    const float* b2   = (const float*)d_in[8];
    const float* m2   = (const float*)d_in[9];
    const float* v2   = (const float*)d_in[10];
    const float* fc1w = (const float*)d_in[11];
    const float* fc2w = (const float*)d_in[12];
    const float* fc3w = (const float*)d_in[13];
    float* out = (float*)d_out;

    char* ws = (char*)d_ws;
    __hip_bfloat16* p1bf = (__hip_bfloat16*)(ws + 0);
    float*          a2t  = (float*)(ws + 25690112);
    __hip_bfloat16* w2s  = (__hip_bfloat16*)(ws + 77070336);
    float*          sc2  = (float*)(ws + 77955072);
    // region-0 reuse after conv2m consumes p1bf:
    __hip_bfloat16* p2bf = (__hip_bfloat16*)(ws + 0);        // 512*6272 bf16
    float*          part = (float*)(ws + 6422528);           // 7*512*1152 fp32
    float*          s3   = (float*)(ws + 22937600);          // 512*1152 fp32
    float*          h2   = (float*)(ws + 25296896);          // 512*128 fp32
    // a2t region reuse after stage2 consumes a2t:
    short*          w1s  = (short*)(ws + 25690112);          // 3*1152*6272 bf16

    prep2_kernel  <<<576,  256, 0, stream>>>(w2, g2, v2, w2s, sc2);
    stage1_kernel <<<6272, 256, 0, stream>>>(x, w1, g1, b1, m1, v1, p1bf);
    conv2m_kernel <<<1024, 256, 0, stream>>>((const short*)p1bf, (const short*)w2s,
                                             sc2, b2, m2, a2t);
    stage2_kernel <<<1568, 256, 0, stream>>>(a2t, p2bf);
    prep_fc1_kernel<<<3528, 256, 0, stream>>>(fc1w, w1s);    // overlays dead a2t
    fc1m_kernel   <<<dim3(9, 8, 7), 256, 0, stream>>>((const short*)p2bf, w1s, part);
    lif2_kernel   <<<288,  256, 0, stream>>>(part, s3);
    gemm_nt_kernel<<<dim3(2, 16), 256, 0, stream>>>(s3, fc2w, h2, 512, 128, 1152);
    tail_kernel   <<<64,   128, 0, stream>>>(h2, fc3w, out);
}

// Round 8
// 439.100 us; speedup vs baseline: 2.5670x; 1.0618x over previous
//
#include <hip/hip_runtime.h>
#include <hip/hip_bf16.h>
#include <cstddef>

// SNN forward, T=8, B=64.
// conv2, fc1, fc2 all on bf16 MFMA with EXACT 3-way bf16 weight splits
// (w = hi+mid+lo exactly; spikes are {0,1}, exact in bf16; fp32 MFMA accum ->
//  only summation-order differences vs the fp32 reference).
//
// Workspace layout (bytes), high water 77,955,584:
//   [0,          25690112)  p1bf  bf16 [TB=512][196][ci=128]  stage-1 spikes
//        region reused after conv2m:
//          p2bf [0,        6422528)   bf16 [512][6272]    stage-2 spikes
//          part [6422528,  22937600)  fp32 [7][512][1152] fc1 split-K partials
//          s3bf [22937600, 24117248)  bf16 [512][1152]    LIF3 spikes
//   [25690112,  77070336)  a2t   fp32 [512][196][128]     conv2+bn2 pre-acts
//        region reused after stage2:
//          w1s  [25690112, 69042176)  bf16 [3][1152][6272] fc1 weight splits
//   [77070336,  77955072)  w2s   bf16 [3][9][128][128]    conv2 weight splits
//   [77955072,  77955584)  sc2   fp32 [128]

typedef __attribute__((ext_vector_type(8))) short  short8;
typedef __attribute__((ext_vector_type(4))) float  f32x4;
typedef __attribute__((ext_vector_type(8))) __bf16 bf16x8;

__device__ inline short f2bf_bits(float x) {
    __hip_bfloat16 h = __float2bfloat16(x);
    return *reinterpret_cast<short*>(&h);
}
__device__ inline float bfbits2f(short b) {
    __hip_bfloat16 h;
    *reinterpret_cast<short*>(&h) = b;
    return __bfloat162float(h);
}

// ---------------- prep: 3-way bf16 split of conv2 weights, bn2 scale --------
__global__ __launch_bounds__(256) void prep2_kernel(
    const float* __restrict__ w2, const float* __restrict__ g2,
    const float* __restrict__ v2, __hip_bfloat16* __restrict__ w2s,
    float* __restrict__ sc2)
{
    int id = blockIdx.x * 256 + threadIdx.x;     // k*16384 + co*128 + ci, grid 576
    if (id < 128) sc2[id] = g2[id] / sqrtf(v2[id] + 1e-5f);
    int ci = id & 127;
    int co = (id >> 7) & 127;
    int k  = id >> 14;                            // 0..8
    float w  = w2[(co * 128 + ci) * 9 + k];
    float hi = __bfloat162float(__float2bfloat16(w));
    float r1 = w - hi;
    float md = __bfloat162float(__float2bfloat16(r1));
    float r2 = r1 - md;                           // exactly representable in bf16
    size_t base = ((size_t)k * 128 + co) * 128 + ci;
    const size_t SPL = 9 * 128 * 128;
    w2s[0 * SPL + base] = __float2bfloat16(hi);
    w2s[1 * SPL + base] = __float2bfloat16(md);
    w2s[2 * SPL + base] = __float2bfloat16(r2);
}

// ---------------- prep: 3-way bf16 split of fc1 weights ---------------------
__global__ __launch_bounds__(256) void prep_fc1_kernel(
    const float* __restrict__ w, short* __restrict__ w1s)
{
    int id = blockIdx.x * 256 + threadIdx.x;      // n*784 + koct, grid 3528
    int koct = id % 784;
    int n    = id / 784;
    const float* src = w + (size_t)n * 6272 + koct * 8;
    float4 va = *(const float4*)src;
    float4 vb = *(const float4*)(src + 4);
    float wv[8] = {va.x, va.y, va.z, va.w, vb.x, vb.y, vb.z, vb.w};
    short8 hi8, md8, lo8;
#pragma unroll
    for (int e = 0; e < 8; ++e) {
        float x  = wv[e];
        short hb = f2bf_bits(x);
        float r1 = x - bfbits2f(hb);
        short mb = f2bf_bits(r1);
        float r2 = r1 - bfbits2f(mb);
        hi8[e] = hb; md8[e] = mb; lo8[e] = f2bf_bits(r2);
    }
    const size_t SPL = (size_t)1152 * 6272;
    size_t base = (size_t)n * 6272 + koct * 8;
    *(short8*)&w1s[0 * SPL + base] = hi8;
    *(short8*)&w1s[1 * SPL + base] = md8;
    *(short8*)&w1s[2 * SPL + base] = lo8;
}

// ---------- stage 1: conv1 + bn1 + 8-step IF scan + 2x2 maxpool -> bf16 -----
__global__ __launch_bounds__(256) void stage1_kernel(
    const float* __restrict__ x,  const float* __restrict__ w1,
    const float* __restrict__ g1, const float* __restrict__ b1,
    const float* __restrict__ m1, const float* __restrict__ v1,
    __hip_bfloat16* __restrict__ p1bf)
{
    int id = blockIdx.x * 256 + threadIdx.x;     // (b*196 + p)*128 + c, exact grid
    int c  = id & 127;
    int bp = id >> 7;
    int p  = bp % 196;
    int b  = bp / 196;
    int ph = p / 14, pw = p % 14;

    float scale = g1[c] / sqrtf(v1[c] + 1e-5f);
    float mu = m1[c], beta = b1[c];
    float wl[9];
#pragma unroll
    for (int k = 0; k < 9; ++k) wl[k] = w1[c * 9 + k];

    const float* xb = x + b * 784;
    float y[4];
#pragma unroll
    for (int i = 0; i < 4; ++i) {
        int h = 2 * ph + (i >> 1);
        int w = 2 * pw + (i & 1);
        float acc = 0.f;
#pragma unroll
        for (int kh = 0; kh < 3; ++kh) {
#pragma unroll
            for (int kw = 0; kw < 3; ++kw) {
                int hh = h + kh - 1, ww = w + kw - 1;
                if ((unsigned)hh < 28u && (unsigned)ww < 28u)
                    acc += xb[hh * 28 + ww] * wl[kh * 3 + kw];
            }
        }
        y[i] = (acc - mu) * scale + beta;        // same op order as reference BN
    }

    float v0 = 0.f, v1m = 0.f, v2m = 0.f, v3m = 0.f;
#pragma unroll
    for (int t = 0; t < 8; ++t) {
        float any = 0.f;
        v0  += y[0]; if (v0  >= 1.0f) { any = 1.0f; v0  = 0.0f; }
        v1m += y[1]; if (v1m >= 1.0f) { any = 1.0f; v1m = 0.0f; }
        v2m += y[2]; if (v2m >= 1.0f) { any = 1.0f; v2m = 0.0f; }
        v3m += y[3]; if (v3m >= 1.0f) { any = 1.0f; v3m = 0.0f; }
        p1bf[((size_t)(t * 64 + b) * 196 + p) * 128 + c] = __float2bfloat16(any);
    }
}

// ---------------- conv2 + bn2 via MFMA (implicit GEMM), v2 ------------------
// ci processed in two 64-ci halves -> LDS 34.8 KB -> 4 blocks/CU.
// Octet swizzle keyed on input-cell pos&7: within any 16-lane MFMA group the
// lanes' cells are pos_out+const -> bank-quads tiled exactly 2x (free).
__global__ __launch_bounds__(256, 4) void conv2m_kernel(
    const short* __restrict__ p1bf, const short* __restrict__ w2s,
    const float* __restrict__ sc2,  const float* __restrict__ b2,
    const float* __restrict__ m2,   float* __restrict__ a2t)
{
    __shared__ short patch[272 * 64];            // 17x16 cells x 64 ci, 34,816 B
    int bx   = blockIdx.x;
    int tb   = bx >> 1;
    int ch   = bx & 1;
    int tid  = threadIdx.x;
    int lane = tid & 63;
    int wv   = tid >> 6;
    int wm   = wv >> 1, wn = wv & 1;
    int l15  = lane & 15, lg = lane >> 4;

    const short8 z8 = {0, 0, 0, 0, 0, 0, 0, 0};
    // zero border cells once (borders stay zero across both halves)
    for (int idx = tid; idx < 76 * 8; idx += 256) {
        int cell = idx >> 3, q = idx & 7;
        int prow, pcol;
        if (cell < 48) {
            int g = cell >> 4;
            prow = (g == 0) ? 0 : ((g == 1) ? 15 : 16);
            pcol = cell & 15;
        } else {
            int e = cell - 48;
            prow = 1 + (e >> 1);
            pcol = (e & 1) ? 15 : 0;
        }
        *(short8*)&patch[(prow * 16 + pcol) * 64 + q * 8] = z8;
    }

    int abase[7], pbase[7];
#pragma unroll
    for (int mi = 0; mi < 7; ++mi) {
        int pos = (wm * 6 + mi) * 16 + l15;      // wm0: tiles 0..6, wm1: 6..12 (dup)
        int r = pos / 14, c = pos - r * 14;
        abase[mi] = r * 16 + c;
        pbase[mi] = pos;
    }
    int co0 = ch * 64 + wn * 32;

    f32x4 acc[7][2];
#pragma unroll
    for (int mi = 0; mi < 7; ++mi) {
        acc[mi][0] = (f32x4){0.f, 0.f, 0.f, 0.f};
        acc[mi][1] = (f32x4){0.f, 0.f, 0.f, 0.f};
    }

    const short* src = p1bf + (size_t)tb * (196 * 128);
    const size_t SPL = 9 * 128 * 128;

    for (int half = 0; half < 2; ++half) {
        if (half) __syncthreads();               // all reads of previous half done
        for (int idx = tid; idx < 196 * 8; idx += 256) {
            int pos = idx >> 3, q = idx & 7;
            short8 v = *(const short8*)&src[pos * 128 + half * 64 + q * 8];
            int h = pos / 14, w = pos - h * 14;
            int lpos = (h + 1) * 16 + (w + 1);
            *(short8*)&patch[lpos * 64 + ((q ^ (pos & 7)) << 3)] = v;
        }
        __syncthreads();

        for (int c2 = 0; c2 < 2; ++c2) {
            int cibase = half * 64 + c2 * 32;
#pragma unroll
            for (int tap = 0; tap < 9; ++tap) {
                const int t16 = (tap / 3) * 16 + (tap % 3);
                const int tc  = (tap / 3 - 1) * 14 + (tap % 3) - 1;   // input-pos delta
                short8 bfr[3][2];
#pragma unroll
                for (int s = 0; s < 3; ++s)
#pragma unroll
                    for (int nt = 0; nt < 2; ++nt)
                        bfr[s][nt] = *(const short8*)&w2s[s * SPL +
                            ((size_t)tap * 128 + co0 + nt * 16 + l15) * 128 + cibase + lg * 8];
#pragma unroll
                for (int mi = 0; mi < 7; ++mi) {
                    int lpos = abase[mi] + t16;
                    int q2 = (c2 * 4 + lg) ^ ((pbase[mi] + tc) & 7);
                    short8 av = *(const short8*)&patch[lpos * 64 + q2 * 8];
                    if (wm == 1 && mi == 6 && l15 >= 4) av = z8;      // mask fake m
                    bf16x8 a = __builtin_bit_cast(bf16x8, av);
#pragma unroll
                    for (int s = 0; s < 3; ++s)
#pragma unroll
                        for (int nt = 0; nt < 2; ++nt)
                            acc[mi][nt] = __builtin_amdgcn_mfma_f32_16x16x32_bf16(
                                a, __builtin_bit_cast(bf16x8, bfr[s][nt]), acc[mi][nt], 0, 0, 0);
                }
            }
        }
    }

    float scv[2], mv[2], bv[2];
#pragma unroll
    for (int nt = 0; nt < 2; ++nt) {
        int co = co0 + nt * 16 + l15;
        scv[nt] = sc2[co]; mv[nt] = m2[co]; bv[nt] = b2[co];
    }
#pragma unroll
    for (int mi = 0; mi < 7; ++mi) {
        int mt = wm * 6 + mi;
#pragma unroll
        for (int nt = 0; nt < 2; ++nt) {
            int co = co0 + nt * 16 + l15;
#pragma unroll
            for (int reg = 0; reg < 4; ++reg) {
                int pos = mt * 16 + lg * 4 + reg;
                if (pos < 196)
                    a2t[((size_t)tb * 196 + pos) * 128 + co] =
                        (acc[mi][nt][reg] - mv[nt]) * scv[nt] + bv[nt];
            }
        }
    }
}

// -------- stage 2: 8-step IF scan over a2t + 2x2 maxpool -> p2 bf16 ---------
__global__ __launch_bounds__(256) void stage2_kernel(
    const float* __restrict__ a2t, __hip_bfloat16* __restrict__ p2)
{
    int id = blockIdx.x * 256 + threadIdx.x;     // (b*49 + p)*128 + c, exact grid
    int c  = id & 127;
    int bp = id >> 7;
    int p  = bp % 49;
    int b  = bp / 49;
    int ph = p / 7, pw = p % 7;
    int s0 = (2 * ph) * 14 + 2 * pw;

    float v0 = 0.f, v1 = 0.f, v2 = 0.f, v3 = 0.f;
#pragma unroll
    for (int t = 0; t < 8; ++t) {
        const float* base = a2t + ((size_t)(t * 64 + b) * 196) * 128 + c;
        float x0 = base[(s0) * 128],      x1 = base[(s0 + 1) * 128];
        float x2 = base[(s0 + 14) * 128], x3 = base[(s0 + 15) * 128];
        float any = 0.f;
        v0 += x0; if (v0 >= 1.0f) { any = 1.0f; v0 = 0.0f; }
        v1 += x1; if (v1 >= 1.0f) { any = 1.0f; v1 = 0.0f; }
        v2 += x2; if (v2 >= 1.0f) { any = 1.0f; v2 = 0.0f; }
        v3 += x3; if (v3 >= 1.0f) { any = 1.0f; v3 = 0.0f; }
        p2[(size_t)(t * 64 + b) * 6272 + c * 49 + p] = __float2bfloat16(any);
    }
}

// ---------------- fc1 via MFMA, split-K=7 -----------------------------------
// Grid (8 m, 9 n, 7 kz): consecutive blocks share the same B panel (L2 reuse).
__global__ __launch_bounds__(256, 2) void fc1m_kernel(
    const short* __restrict__ A,     // p2 bf16 [512][6272]
    const short* __restrict__ Bsp,   // w1s bf16 [3][1152][6272]
    float* __restrict__ part)        // [7][512][1152]
{
    __shared__ short At[64 * 64];
    const int m0 = blockIdx.x * 64;
    const int n0 = blockIdx.y * 128;
    const int kz = blockIdx.z;                   // K-chunk: 14 steps of 64
    const int tid  = threadIdx.x;
    const int lane = tid & 63;
    const int wv   = tid >> 6;
    const int wm = wv >> 1, wn = wv & 1;
    const int l15 = lane & 15, lg = lane >> 4;
    const size_t SPL = (size_t)1152 * 6272;

    f32x4 acc[2][4];
#pragma unroll
    for (int mi = 0; mi < 2; ++mi)
#pragma unroll
        for (int nt = 0; nt < 4; ++nt)
            acc[mi][nt] = (f32x4){0.f, 0.f, 0.f, 0.f};

    for (int ks = 0; ks < 14; ++ks) {
        int k0 = kz * 896 + ks * 64;
#pragma unroll
        for (int pp = 0; pp < 2; ++pp) {
            int i = pp * 256 + tid;
            int row = i >> 3, q = i & 7;
            short8 v = *(const short8*)&A[(size_t)(m0 + row) * 6272 + k0 + ((q ^ (row & 7)) << 3)];
            *(short8*)&At[row * 64 + q * 8] = v;
        }
        __syncthreads();

#pragma unroll
        for (int kh = 0; kh < 2; ++kh) {
            bf16x8 a[2];
#pragma unroll
            for (int mi = 0; mi < 2; ++mi) {
                int r = wm * 32 + mi * 16 + l15;
                int q = (kh * 4 + lg) ^ (r & 7);
                a[mi] = __builtin_bit_cast(bf16x8, *(const short8*)&At[r * 64 + q * 8]);
            }
#pragma unroll
            for (int s = 0; s < 3; ++s) {
#pragma unroll
                for (int nt = 0; nt < 4; ++nt) {
                    bf16x8 b = __builtin_bit_cast(bf16x8, *(const short8*)&Bsp[s * SPL +
                        (size_t)(n0 + wn * 64 + nt * 16 + l15) * 6272 + k0 + kh * 32 + lg * 8]);
                    acc[0][nt] = __builtin_amdgcn_mfma_f32_16x16x32_bf16(a[0], b, acc[0][nt], 0, 0, 0);
                    acc[1][nt] = __builtin_amdgcn_mfma_f32_16x16x32_bf16(a[1], b, acc[1][nt], 0, 0, 0);
                }
            }
        }
        __syncthreads();
    }

    float* dst = part + (size_t)kz * (512 * 1152);
#pragma unroll
    for (int mi = 0; mi < 2; ++mi) {
#pragma unroll
        for (int nt = 0; nt < 4; ++nt) {
            int n = n0 + wn * 64 + nt * 16 + l15;
#pragma unroll
            for (int reg = 0; reg < 4; ++reg) {
                int m = m0 + wm * 32 + mi * 16 + lg * 4 + reg;
                dst[(size_t)m * 1152 + n] = acc[mi][nt][reg];
            }
        }
    }
}

// --------- fused: reduce 7 fc1 partials + LIF scan -> s3 (bf16 spikes) ------
__global__ __launch_bounds__(256) void lif2_kernel(
    const float* __restrict__ part, __hip_bfloat16* __restrict__ s3)
{
    int id = blockIdx.x * 256 + threadIdx.x;     // b*1152 + f, grid 288 exact
    int f = id % 1152;
    int b = id / 1152;
    const size_t S = (size_t)512 * 1152;
    float v = 0.f;
#pragma unroll
    for (int t = 0; t < 8; ++t) {
        size_t off = (size_t)(t * 64 + b) * 1152 + f;
        float x = part[off];
#pragma unroll
        for (int s = 1; s < 7; ++s) x += part[s * S + off];
        v = v + (x - v) * 0.5f;
        s3[off] = __float2bfloat16((v >= 1.0f) ? 1.0f : 0.0f);
        if (v >= 1.0f) v = 0.0f;
    }
}

// -------- fused tail: fc2 (MFMA, m-dim = 8 timesteps) -> LIF -> fc3 -> LIF
//          -> mean over T.  One block per image b; 4 waves, each 2 o-tiles. --
__global__ __launch_bounds__(256) void fc2tail_kernel(
    const short* __restrict__ s3bf,   // [512][1152] bf16 spikes
    const float* __restrict__ fc2w,   // [128][1152] fp32
    const float* __restrict__ fc3w,   // [10][128]   fp32
    float* __restrict__ out)          // [64][10]
{
    __shared__ float h2[8][128];
    __shared__ float s4[8][128];
    __shared__ float dd[8][10];
    int b    = blockIdx.x;
    int tid  = threadIdx.x;
    int lane = tid & 63;
    int wv   = tid >> 6;
    int l15  = lane & 15, lg = lane >> 4;

    const short8 z8 = {0, 0, 0, 0, 0, 0, 0, 0};
    f32x4 acc[2] = {(f32x4){0.f, 0.f, 0.f, 0.f}, (f32x4){0.f, 0.f, 0.f, 0.f}};

    for (int ks = 0; ks < 36; ++ks) {
        // A-frag: row m = timestep t = l15 (rows 8..15 are zero padding)
        short8 av = (l15 < 8)
            ? *(const short8*)&s3bf[(size_t)(l15 * 64 + b) * 1152 + ks * 32 + lg * 8]
            : z8;
        bf16x8 a = __builtin_bit_cast(bf16x8, av);
#pragma unroll
        for (int nt = 0; nt < 2; ++nt) {
            int o = wv * 32 + nt * 16 + l15;
            const float* wp = &fc2w[(size_t)o * 1152 + ks * 32 + lg * 8];
            float4 wa = *(const float4*)wp;
            float4 wb = *(const float4*)(wp + 4);
            float wvv[8] = {wa.x, wa.y, wa.z, wa.w, wb.x, wb.y, wb.z, wb.w};
            short8 hi8, md8, lo8;
#pragma unroll
            for (int e = 0; e < 8; ++e) {
                float xw = wvv[e];
                short hb = f2bf_bits(xw);
                float r1 = xw - bfbits2f(hb);
                short mb = f2bf_bits(r1);
                float r2 = r1 - bfbits2f(mb);
                hi8[e] = hb; md8[e] = mb; lo8[e] = f2bf_bits(r2);
            }
            acc[nt] = __builtin_amdgcn_mfma_f32_16x16x32_bf16(
                a, __builtin_bit_cast(bf16x8, hi8), acc[nt], 0, 0, 0);
            acc[nt] = __builtin_amdgcn_mfma_f32_16x16x32_bf16(
                a, __builtin_bit_cast(bf16x8, md8), acc[nt], 0, 0, 0);
            acc[nt] = __builtin_amdgcn_mfma_f32_16x16x32_bf16(
                a, __builtin_bit_cast(bf16x8, lo8), acc[nt], 0, 0, 0);
        }
    }
    // C layout: col = l15 (o within tile), row = lg*4+reg (timestep, valid <8)
#pragma unroll
    for (int nt = 0; nt < 2; ++nt) {
#pragma unroll
        for (int reg = 0; reg < 4; ++reg) {
            int t = lg * 4 + reg;
            if (t < 8) h2[t][wv * 32 + nt * 16 + l15] = acc[nt][reg];
        }
    }
    __syncthreads();

    if (tid < 128) {
        float v = 0.f;
#pragma unroll
        for (int t = 0; t < 8; ++t) {
            float xv = h2[t][tid];
            v = v + (xv - v) * 0.5f;
            s4[t][tid] = (v >= 1.0f) ? 1.0f : 0.0f;
            if (v >= 1.0f) v = 0.0f;
        }
    }
    __syncthreads();
    if (tid < 80) {
        int t = tid / 10, o = tid - (tid / 10) * 10;
        float dot = 0.f;
        for (int k = 0; k < 128; ++k) dot += s4[t][k] * fc3w[o * 128 + k];
        dd[t][o] = dot;
    }
    __syncthreads();
    if (tid < 10) {
        float vv = 0.f, cnt = 0.f;
#pragma unroll
        for (int t = 0; t < 8; ++t) {
            float xv = dd[t][tid];
            vv = vv + (xv - vv) * 0.5f;
            if (vv >= 1.0f) { cnt += 1.0f; vv = 0.0f; }
        }
        out[b * 10 + tid] = cnt * 0.125f;
    }
}

extern "C" void kernel_launch(void* const* d_in, const int* in_sizes, int n_in,
                              void* d_out, int out_size, void* d_ws, size_t ws_size,
                              hipStream_t stream)
{
    (void)in_sizes; (void)n_in; (void)out_size; (void)ws_size;
    const float* x    = (const float*)d_in[0];
    const float* w1   = (const float*)d_in[1];
    const float* g1   = (const float*)d_in[2];
    const float* b1   = (const float*)d_in[3];
    const float* m1   = (const float*)d_in[4];
    const float* v1   = (const float*)d_in[5];
    const float* w2   = (const float*)d_in[6];
    const float* g2   = (const float*)d_in[7];
    const float* b2   = (const float*)d_in[8];
    const float* m2   = (const float*)d_in[9];
    const float* v2   = (const float*)d_in[10];
    const float* fc1w = (const float*)d_in[11];
    const float* fc2w = (const float*)d_in[12];
    const float* fc3w = (const float*)d_in[13];
    float* out = (float*)d_out;

    char* ws = (char*)d_ws;
    __hip_bfloat16* p1bf = (__hip_bfloat16*)(ws + 0);
    float*          a2t  = (float*)(ws + 25690112);
    __hip_bfloat16* w2s  = (__hip_bfloat16*)(ws + 77070336);
    float*          sc2  = (float*)(ws + 77955072);
    // region-0 reuse after conv2m consumes p1bf:
    __hip_bfloat16* p2bf = (__hip_bfloat16*)(ws + 0);        // 512*6272 bf16
    float*          part = (float*)(ws + 6422528);           // 7*512*1152 fp32
    __hip_bfloat16* s3bf = (__hip_bfloat16*)(ws + 22937600); // 512*1152 bf16
    // a2t region reuse after stage2 consumes a2t:
    short*          w1s  = (short*)(ws + 25690112);          // 3*1152*6272 bf16

    prep2_kernel   <<<576,  256, 0, stream>>>(w2, g2, v2, w2s, sc2);
    stage1_kernel  <<<6272, 256, 0, stream>>>(x, w1, g1, b1, m1, v1, p1bf);
    conv2m_kernel  <<<1024, 256, 0, stream>>>((const short*)p1bf, (const short*)w2s,
                                              sc2, b2, m2, a2t);
    stage2_kernel  <<<1568, 256, 0, stream>>>(a2t, p2bf);
    prep_fc1_kernel<<<3528, 256, 0, stream>>>(fc1w, w1s);    // overlays dead a2t
    fc1m_kernel    <<<dim3(8, 9, 7), 256, 0, stream>>>((const short*)p2bf, w1s, part);
    lif2_kernel    <<<288,  256, 0, stream>>>(part, s3bf);
    fc2tail_kernel <<<64,   256, 0, stream>>>((const short*)s3bf, fc2w, fc3w, out);
}

// Round 12
// 430.629 us; speedup vs baseline: 2.6175x; 1.0197x over previous
//
#include <hip/hip_runtime.h>
#include <hip/hip_bf16.h>
#include <cstddef>

// SNN forward, T=8, B=64.
// conv2, fc1, fc2 all on bf16 MFMA with EXACT 3-way bf16 weight splits
// (w = hi+mid+lo exactly; spikes are {0,1}, exact in bf16; fp32 MFMA accum ->
//  only summation-order differences vs the fp32 reference).
//
// conv2m v3: full-128ci patch (69.6KB, 2 blk/CU — the 4-blk/CU variant tripled
// HBM traffic via L2 thrash), pos&7 octet swizzle (proven conflict-free),
// ch-major block decode (tb pair shares XCD L2), B-register double-buffering
// (tap k+1 loads in flight under tap k's 42 MFMAs).
//
// Workspace layout (bytes), high water 77,955,584:
//   [0,          25690112)  p1bf  bf16 [TB=512][196][ci=128]  stage-1 spikes
//        region reused after conv2m:
//          p2bf [0,        6422528)   bf16 [512][6272]    stage-2 spikes
//          part [6422528,  22937600)  fp32 [7][512][1152] fc1 split-K partials
//          s3bf [22937600, 24117248)  bf16 [512][1152]    LIF3 spikes
//   [25690112,  77070336)  a2t   fp32 [512][196][128]     conv2+bn2 pre-acts
//        region reused after stage2:
//          w1s  [25690112, 69042176)  bf16 [3][1152][6272] fc1 weight splits
//   [77070336,  77955072)  w2s   bf16 [3][9][128][128]    conv2 weight splits
//   [77955072,  77955584)  sc2   fp32 [128]

typedef __attribute__((ext_vector_type(8))) short  short8;
typedef __attribute__((ext_vector_type(4))) float  f32x4;
typedef __attribute__((ext_vector_type(8))) __bf16 bf16x8;

__device__ inline short f2bf_bits(float x) {
    __hip_bfloat16 h = __float2bfloat16(x);
    return *reinterpret_cast<short*>(&h);
}
__device__ inline float bfbits2f(short b) {
    __hip_bfloat16 h;
    *reinterpret_cast<short*>(&h) = b;
    return __bfloat162float(h);
}

// ---------------- prep: 3-way bf16 split of conv2 weights, bn2 scale --------
__global__ __launch_bounds__(256) void prep2_kernel(
    const float* __restrict__ w2, const float* __restrict__ g2,
    const float* __restrict__ v2, __hip_bfloat16* __restrict__ w2s,
    float* __restrict__ sc2)
{
    int id = blockIdx.x * 256 + threadIdx.x;     // k*16384 + co*128 + ci, grid 576
    if (id < 128) sc2[id] = g2[id] / sqrtf(v2[id] + 1e-5f);
    int ci = id & 127;
    int co = (id >> 7) & 127;
    int k  = id >> 14;                            // 0..8
    float w  = w2[(co * 128 + ci) * 9 + k];
    float hi = __bfloat162float(__float2bfloat16(w));
    float r1 = w - hi;
    float md = __bfloat162float(__float2bfloat16(r1));
    float r2 = r1 - md;                           // exactly representable in bf16
    size_t base = ((size_t)k * 128 + co) * 128 + ci;
    const size_t SPL = 9 * 128 * 128;
    w2s[0 * SPL + base] = __float2bfloat16(hi);
    w2s[1 * SPL + base] = __float2bfloat16(md);
    w2s[2 * SPL + base] = __float2bfloat16(r2);
}

// ---------------- prep: 3-way bf16 split of fc1 weights ---------------------
__global__ __launch_bounds__(256) void prep_fc1_kernel(
    const float* __restrict__ w, short* __restrict__ w1s)
{
    int id = blockIdx.x * 256 + threadIdx.x;      // n*784 + koct, grid 3528
    int koct = id % 784;
    int n    = id / 784;
    const float* src = w + (size_t)n * 6272 + koct * 8;
    float4 va = *(const float4*)src;
    float4 vb = *(const float4*)(src + 4);
    float wv[8] = {va.x, va.y, va.z, va.w, vb.x, vb.y, vb.z, vb.w};
    short8 hi8, md8, lo8;
#pragma unroll
    for (int e = 0; e < 8; ++e) {
        float x  = wv[e];
        short hb = f2bf_bits(x);
        float r1 = x - bfbits2f(hb);
        short mb = f2bf_bits(r1);
        float r2 = r1 - bfbits2f(mb);
        hi8[e] = hb; md8[e] = mb; lo8[e] = f2bf_bits(r2);
    }
    const size_t SPL = (size_t)1152 * 6272;
    size_t base = (size_t)n * 6272 + koct * 8;
    *(short8*)&w1s[0 * SPL + base] = hi8;
    *(short8*)&w1s[1 * SPL + base] = md8;
    *(short8*)&w1s[2 * SPL + base] = lo8;
}

// ---------- stage 1: conv1 + bn1 + 8-step IF scan + 2x2 maxpool -> bf16 -----
__global__ __launch_bounds__(256) void stage1_kernel(
    const float* __restrict__ x,  const float* __restrict__ w1,
    const float* __restrict__ g1, const float* __restrict__ b1,
    const float* __restrict__ m1, const float* __restrict__ v1,
    __hip_bfloat16* __restrict__ p1bf)
{
    int id = blockIdx.x * 256 + threadIdx.x;     // (b*196 + p)*128 + c, exact grid
    int c  = id & 127;
    int bp = id >> 7;
    int p  = bp % 196;
    int b  = bp / 196;
    int ph = p / 14, pw = p % 14;

    float scale = g1[c] / sqrtf(v1[c] + 1e-5f);
    float mu = m1[c], beta = b1[c];
    float wl[9];
#pragma unroll
    for (int k = 0; k < 9; ++k) wl[k] = w1[c * 9 + k];

    const float* xb = x + b * 784;
    float y[4];
#pragma unroll
    for (int i = 0; i < 4; ++i) {
        int h = 2 * ph + (i >> 1);
        int w = 2 * pw + (i & 1);
        float acc = 0.f;
#pragma unroll
        for (int kh = 0; kh < 3; ++kh) {
#pragma unroll
            for (int kw = 0; kw < 3; ++kw) {
                int hh = h + kh - 1, ww = w + kw - 1;
                if ((unsigned)hh < 28u && (unsigned)ww < 28u)
                    acc += xb[hh * 28 + ww] * wl[kh * 3 + kw];
            }
        }
        y[i] = (acc - mu) * scale + beta;        // same op order as reference BN
    }

    float v0 = 0.f, v1m = 0.f, v2m = 0.f, v3m = 0.f;
#pragma unroll
    for (int t = 0; t < 8; ++t) {
        float any = 0.f;
        v0  += y[0]; if (v0  >= 1.0f) { any = 1.0f; v0  = 0.0f; }
        v1m += y[1]; if (v1m >= 1.0f) { any = 1.0f; v1m = 0.0f; }
        v2m += y[2]; if (v2m >= 1.0f) { any = 1.0f; v2m = 0.0f; }
        v3m += y[3]; if (v3m >= 1.0f) { any = 1.0f; v3m = 0.0f; }
        p1bf[((size_t)(t * 64 + b) * 196 + p) * 128 + c] = __float2bfloat16(any);
    }
}

// ---------------- conv2 + bn2 via MFMA (implicit GEMM), v3 ------------------
// Full 128-ci patch staged once (69.6 KB LDS, 2 blocks/CU).
// Octet swizzle keyed on input-cell pos&7 (conflict-free, proven r8).
// ch-major block decode: tb's co-pair lands on the SAME XCD (bx, bx+512).
// B double-buffer: next tap's 6 B-frags load under current tap's 42 MFMAs.
__global__ __launch_bounds__(256, 2) void conv2m_kernel(
    const short* __restrict__ p1bf, const short* __restrict__ w2s,
    const float* __restrict__ sc2,  const float* __restrict__ b2,
    const float* __restrict__ m2,   float* __restrict__ a2t)
{
    __shared__ short patch[272 * 128];           // 17x16 cells x 128 ci, 69,632 B
    int bx   = blockIdx.x;
    int tb   = bx & 511;
    int ch   = bx >> 9;                          // ch-major: pair shares XCD L2
    int tid  = threadIdx.x;
    int lane = tid & 63;
    int wv   = tid >> 6;
    int wm   = wv >> 1, wn = wv & 1;
    int l15  = lane & 15, lg = lane >> 4;

    const short8 z8 = {0, 0, 0, 0, 0, 0, 0, 0};
    // zero border cells (rows {0,15,16} all cols + cols {0,15} rows 1..14)
    for (int idx = tid; idx < 76 * 16; idx += 256) {
        int cell = idx >> 4, sl = idx & 15;
        int prow, pcol;
        if (cell < 48) {
            int g = cell >> 4;
            prow = (g == 0) ? 0 : ((g == 1) ? 15 : 16);
            pcol = cell & 15;
        } else {
            int e = cell - 48;
            prow = 1 + (e >> 1);
            pcol = (e & 1) ? 15 : 0;
        }
        *(short8*)&patch[(prow * 16 + pcol) * 128 + sl * 8] = z8;
    }
    // stage real cells; octet slot = q ^ (pos&7)  (flips low-3 bits only)
    const short* src = p1bf + (size_t)tb * (196 * 128);
    for (int idx = tid; idx < 196 * 16; idx += 256) {
        int pos = idx >> 4, q = idx & 15;
        short8 v = *(const short8*)&src[pos * 128 + q * 8];
        int h = pos / 14, w = pos - h * 14;
        int lpos = (h + 1) * 16 + (w + 1);
        *(short8*)&patch[lpos * 128 + ((q ^ (pos & 7)) << 3)] = v;
    }
    __syncthreads();

    int abase[7], pbase[7];
#pragma unroll
    for (int mi = 0; mi < 7; ++mi) {
        int pos = (wm * 6 + mi) * 16 + l15;      // wm0: tiles 0..6, wm1: 6..12 (dup)
        int r = pos / 14, c = pos - r * 14;
        abase[mi] = r * 16 + c;
        pbase[mi] = pos;
    }
    int co0 = ch * 64 + wn * 32;

    f32x4 acc[7][2];
#pragma unroll
    for (int mi = 0; mi < 7; ++mi) {
        acc[mi][0] = (f32x4){0.f, 0.f, 0.f, 0.f};
        acc[mi][1] = (f32x4){0.f, 0.f, 0.f, 0.f};
    }

    const size_t SPL = 9 * 128 * 128;
    // B double-buffer: preload (chunk0, tap0)
    short8 bcur[3][2];
#pragma unroll
    for (int s = 0; s < 3; ++s)
#pragma unroll
        for (int nt = 0; nt < 2; ++nt)
            bcur[s][nt] = *(const short8*)&w2s[s * SPL +
                ((size_t)0 * 128 + co0 + nt * 16 + l15) * 128 + 0 * 32 + lg * 8];

#pragma unroll 1
    for (int chunk = 0; chunk < 4; ++chunk) {
#pragma unroll
        for (int tap = 0; tap < 9; ++tap) {
            // issue next (chunk,tap)'s B-loads (clamped dead-load at the end)
            int ntap   = (tap == 8) ? 0 : tap + 1;
            int nchunk = (tap == 8) ? ((chunk < 3) ? chunk + 1 : 3) : chunk;
            short8 bnxt[3][2];
#pragma unroll
            for (int s = 0; s < 3; ++s)
#pragma unroll
                for (int nt = 0; nt < 2; ++nt)
                    bnxt[s][nt] = *(const short8*)&w2s[s * SPL +
                        ((size_t)ntap * 128 + co0 + nt * 16 + l15) * 128 + nchunk * 32 + lg * 8];

            const int t16 = (tap / 3) * 16 + (tap % 3);
            const int tc  = (tap / 3 - 1) * 14 + (tap % 3) - 1;   // input-pos delta
#pragma unroll
            for (int mi = 0; mi < 7; ++mi) {
                int lpos = abase[mi] + t16;
                int q2 = (chunk * 4 + lg) ^ ((pbase[mi] + tc) & 7);
                short8 av = *(const short8*)&patch[lpos * 128 + q2 * 8];
                if (wm == 1 && mi == 6 && l15 >= 4) av = z8;      // mask fake m
                bf16x8 a = __builtin_bit_cast(bf16x8, av);
#pragma unroll
                for (int s = 0; s < 3; ++s)
#pragma unroll
                    for (int nt = 0; nt < 2; ++nt)
                        acc[mi][nt] = __builtin_amdgcn_mfma_f32_16x16x32_bf16(
                            a, __builtin_bit_cast(bf16x8, bcur[s][nt]), acc[mi][nt], 0, 0, 0);
            }
#pragma unroll
            for (int s = 0; s < 3; ++s)
#pragma unroll
                for (int nt = 0; nt < 2; ++nt)
                    bcur[s][nt] = bnxt[s][nt];
        }
    }

    float scv[2], mv[2], bv[2];
#pragma unroll
    for (int nt = 0; nt < 2; ++nt) {
        int co = co0 + nt * 16 + l15;
        scv[nt] = sc2[co]; mv[nt] = m2[co]; bv[nt] = b2[co];
    }
#pragma unroll
    for (int mi = 0; mi < 7; ++mi) {
        int mt = wm * 6 + mi;
#pragma unroll
        for (int nt = 0; nt < 2; ++nt) {
            int co = co0 + nt * 16 + l15;
#pragma unroll
            for (int reg = 0; reg < 4; ++reg) {
                int pos = mt * 16 + lg * 4 + reg;
                if (pos < 196)
                    a2t[((size_t)tb * 196 + pos) * 128 + co] =
                        (acc[mi][nt][reg] - mv[nt]) * scv[nt] + bv[nt];
            }
        }
    }
}

// -------- stage 2: 8-step IF scan over a2t + 2x2 maxpool -> p2 bf16 ---------
__global__ __launch_bounds__(256) void stage2_kernel(
    const float* __restrict__ a2t, __hip_bfloat16* __restrict__ p2)
{
    int id = blockIdx.x * 256 + threadIdx.x;     // (b*49 + p)*128 + c, exact grid
    int c  = id & 127;
    int bp = id >> 7;
    int p  = bp % 49;
    int b  = bp / 49;
    int ph = p / 7, pw = p % 7;
    int s0 = (2 * ph) * 14 + 2 * pw;

    float v0 = 0.f, v1 = 0.f, v2 = 0.f, v3 = 0.f;
#pragma unroll
    for (int t = 0; t < 8; ++t) {
        const float* base = a2t + ((size_t)(t * 64 + b) * 196) * 128 + c;
        float x0 = base[(s0) * 128],      x1 = base[(s0 + 1) * 128];
        float x2 = base[(s0 + 14) * 128], x3 = base[(s0 + 15) * 128];
        float any = 0.f;
        v0 += x0; if (v0 >= 1.0f) { any = 1.0f; v0 = 0.0f; }
        v1 += x1; if (v1 >= 1.0f) { any = 1.0f; v1 = 0.0f; }
        v2 += x2; if (v2 >= 1.0f) { any = 1.0f; v2 = 0.0f; }
        v3 += x3; if (v3 >= 1.0f) { any = 1.0f; v3 = 0.0f; }
        p2[(size_t)(t * 64 + b) * 6272 + c * 49 + p] = __float2bfloat16(any);
    }
}

// ---------------- fc1 via MFMA, split-K=7 -----------------------------------
// Grid (8 m, 9 n, 7 kz): consecutive blocks share the same B panel (L2 reuse).
__global__ __launch_bounds__(256, 2) void fc1m_kernel(
    const short* __restrict__ A,     // p2 bf16 [512][6272]
    const short* __restrict__ Bsp,   // w1s bf16 [3][1152][6272]
    float* __restrict__ part)        // [7][512][1152]
{
    __shared__ short At[64 * 64];
    const int m0 = blockIdx.x * 64;
    const int n0 = blockIdx.y * 128;
    const int kz = blockIdx.z;                   // K-chunk: 14 steps of 64
    const int tid  = threadIdx.x;
    const int lane = tid & 63;
    const int wv   = tid >> 6;
    const int wm = wv >> 1, wn = wv & 1;
    const int l15 = lane & 15, lg = lane >> 4;
    const size_t SPL = (size_t)1152 * 6272;

    f32x4 acc[2][4];
#pragma unroll
    for (int mi = 0; mi < 2; ++mi)
#pragma unroll
        for (int nt = 0; nt < 4; ++nt)
            acc[mi][nt] = (f32x4){0.f, 0.f, 0.f, 0.f};

    for (int ks = 0; ks < 14; ++ks) {
        int k0 = kz * 896 + ks * 64;
#pragma unroll
        for (int pp = 0; pp < 2; ++pp) {
            int i = pp * 256 + tid;
            int row = i >> 3, q = i & 7;
            short8 v = *(const short8*)&A[(size_t)(m0 + row) * 6272 + k0 + ((q ^ (row & 7)) << 3)];
            *(short8*)&At[row * 64 + q * 8] = v;
        }
        __syncthreads();

#pragma unroll
        for (int kh = 0; kh < 2; ++kh) {
            bf16x8 a[2];
#pragma unroll
            for (int mi = 0; mi < 2; ++mi) {
                int r = wm * 32 + mi * 16 + l15;
                int q = (kh * 4 + lg) ^ (r & 7);
                a[mi] = __builtin_bit_cast(bf16x8, *(const short8*)&At[r * 64 + q * 8]);
            }
#pragma unroll
            for (int s = 0; s < 3; ++s) {
#pragma unroll
                for (int nt = 0; nt < 4; ++nt) {
                    bf16x8 b = __builtin_bit_cast(bf16x8, *(const short8*)&Bsp[s * SPL +
                        (size_t)(n0 + wn * 64 + nt * 16 + l15) * 6272 + k0 + kh * 32 + lg * 8]);
                    acc[0][nt] = __builtin_amdgcn_mfma_f32_16x16x32_bf16(a[0], b, acc[0][nt], 0, 0, 0);
                    acc[1][nt] = __builtin_amdgcn_mfma_f32_16x16x32_bf16(a[1], b, acc[1][nt], 0, 0, 0);
                }
            }
        }
        __syncthreads();
    }

    float* dst = part + (size_t)kz * (512 * 1152);
#pragma unroll
    for (int mi = 0; mi < 2; ++mi) {
#pragma unroll
        for (int nt = 0; nt < 4; ++nt) {
            int n = n0 + wn * 64 + nt * 16 + l15;
#pragma unroll
            for (int reg = 0; reg < 4; ++reg) {
                int m = m0 + wm * 32 + mi * 16 + lg * 4 + reg;
                dst[(size_t)m * 1152 + n] = acc[mi][nt][reg];
            }
        }
    }
}

// --------- fused: reduce 7 fc1 partials + LIF scan -> s3 (bf16 spikes) ------
__global__ __launch_bounds__(256) void lif2_kernel(
    const float* __restrict__ part, __hip_bfloat16* __restrict__ s3)
{
    int id = blockIdx.x * 256 + threadIdx.x;     // b*1152 + f, grid 288 exact
    int f = id % 1152;
    int b = id / 1152;
    const size_t S = (size_t)512 * 1152;
    float v = 0.f;
#pragma unroll
    for (int t = 0; t < 8; ++t) {
        size_t off = (size_t)(t * 64 + b) * 1152 + f;
        float x = part[off];
#pragma unroll
        for (int s = 1; s < 7; ++s) x += part[s * S + off];
        v = v + (x - v) * 0.5f;
        s3[off] = __float2bfloat16((v >= 1.0f) ? 1.0f : 0.0f);
        if (v >= 1.0f) v = 0.0f;
    }
}

// -------- fused tail: fc2 (MFMA, m-dim = 8 timesteps) -> LIF -> fc3 -> LIF
//          -> mean over T.  One block per image b; 4 waves, each 2 o-tiles. --
__global__ __launch_bounds__(256) void fc2tail_kernel(
    const short* __restrict__ s3bf,   // [512][1152] bf16 spikes
    const float* __restrict__ fc2w,   // [128][1152] fp32
    const float* __restrict__ fc3w,   // [10][128]   fp32
    float* __restrict__ out)          // [64][10]
{
    __shared__ float h2[8][128];
    __shared__ float s4[8][128];
    __shared__ float dd[8][10];
    int b    = blockIdx.x;
    int tid  = threadIdx.x;
    int lane = tid & 63;
    int wv   = tid >> 6;
    int l15  = lane & 15, lg = lane >> 4;

    const short8 z8 = {0, 0, 0, 0, 0, 0, 0, 0};
    f32x4 acc[2] = {(f32x4){0.f, 0.f, 0.f, 0.f}, (f32x4){0.f, 0.f, 0.f, 0.f}};

    for (int ks = 0; ks < 36; ++ks) {
        // A-frag: row m = timestep t = l15 (rows 8..15 are zero padding)
        short8 av = (l15 < 8)
            ? *(const short8*)&s3bf[(size_t)(l15 * 64 + b) * 1152 + ks * 32 + lg * 8]
            : z8;
        bf16x8 a = __builtin_bit_cast(bf16x8, av);
#pragma unroll
        for (int nt = 0; nt < 2; ++nt) {
            int o = wv * 32 + nt * 16 + l15;
            const float* wp = &fc2w[(size_t)o * 1152 + ks * 32 + lg * 8];
            float4 wa = *(const float4*)wp;
            float4 wb = *(const float4*)(wp + 4);
            float wvv[8] = {wa.x, wa.y, wa.z, wa.w, wb.x, wb.y, wb.z, wb.w};
            short8 hi8, md8, lo8;
#pragma unroll
            for (int e = 0; e < 8; ++e) {
                float xw = wvv[e];
                short hb = f2bf_bits(xw);
                float r1 = xw - bfbits2f(hb);
                short mb = f2bf_bits(r1);
                float r2 = r1 - bfbits2f(mb);
                hi8[e] = hb; md8[e] = mb; lo8[e] = f2bf_bits(r2);
            }
            acc[nt] = __builtin_amdgcn_mfma_f32_16x16x32_bf16(
                a, __builtin_bit_cast(bf16x8, hi8), acc[nt], 0, 0, 0);
            acc[nt] = __builtin_amdgcn_mfma_f32_16x16x32_bf16(
                a, __builtin_bit_cast(bf16x8, md8), acc[nt], 0, 0, 0);
            acc[nt] = __builtin_amdgcn_mfma_f32_16x16x32_bf16(
                a, __builtin_bit_cast(bf16x8, lo8), acc[nt], 0, 0, 0);
        }
    }
    // C layout: col = l15 (o within tile), row = lg*4+reg (timestep, valid <8)
#pragma unroll
    for (int nt = 0; nt < 2; ++nt) {
#pragma unroll
        for (int reg = 0; reg < 4; ++reg) {
            int t = lg * 4 + reg;
            if (t < 8) h2[t][wv * 32 + nt * 16 + l15] = acc[nt][reg];
        }
    }
    __syncthreads();

    if (tid < 128) {
        float v = 0.f;
#pragma unroll
        for (int t = 0; t < 8; ++t) {
            float xv = h2[t][tid];
            v = v + (xv - v) * 0.5f;
            s4[t][tid] = (v >= 1.0f) ? 1.0f : 0.0f;
            if (v >= 1.0f) v = 0.0f;
        }
    }
    __syncthreads();
    if (tid < 80) {
        int t = tid / 10, o = tid - (tid / 10) * 10;
        float dot = 0.f;
        for (int k = 0; k < 128; ++k) dot += s4[t][k] * fc3w[o * 128 + k];
        dd[t][o] = dot;
    }
    __syncthreads();
    if (tid < 10) {
        float vv = 0.f, cnt = 0.f;
#pragma unroll
        for (int t = 0; t < 8; ++t) {
            float xv = dd[t][tid];
            vv = vv + (xv - vv) * 0.5f;
            if (vv >= 1.0f) { cnt += 1.0f; vv = 0.0f; }
        }
        out[b * 10 + tid] = cnt * 0.125f;
    }
}

extern "C" void kernel_launch(void* const* d_in, const int* in_sizes, int n_in,
                              void* d_out, int out_size, void* d_ws, size_t ws_size,
                              hipStream_t stream)
{
    (void)in_sizes; (void)n_in; (void)out_size; (void)ws_size;
    const float* x    = (const float*)d_in[0];
    const float* w1   = (const float*)d_in[1];
    const float* g1   = (const float*)d_in[2];
    const float* b1   = (const float*)d_in[3];
    const float* m1   = (const float*)d_in[4];
    const float* v1   = (const float*)d_in[5];
    const float* w2   = (const float*)d_in[6];
    const float* g2   = (const float*)d_in[7];
    const float* b2   = (const float*)d_in[8];
    const float* m2   = (const float*)d_in[9];
    const float* v2   = (const float*)d_in[10];
    const float* fc1w = (const float*)d_in[11];
    const float* fc2w = (const float*)d_in[12];
    const float* fc3w = (const float*)d_in[13];
    float* out = (float*)d_out;

    char* ws = (char*)d_ws;
    __hip_bfloat16* p1bf = (__hip_bfloat16*)(ws + 0);
    float*          a2t  = (float*)(ws + 25690112);
    __hip_bfloat16* w2s  = (__hip_bfloat16*)(ws + 77070336);
    float*          sc2  = (float*)(ws + 77955072);
    // region-0 reuse after conv2m consumes p1bf:
    __hip_bfloat16* p2bf = (__hip_bfloat16*)(ws + 0);        // 512*6272 bf16
    float*          part = (float*)(ws + 6422528);           // 7*512*1152 fp32
    __hip_bfloat16* s3bf = (__hip_bfloat16*)(ws + 22937600); // 512*1152 bf16
    // a2t region reuse after stage2 consumes a2t:
    short*          w1s  = (short*)(ws + 25690112);          // 3*1152*6272 bf16

    prep2_kernel   <<<576,  256, 0, stream>>>(w2, g2, v2, w2s, sc2);
    stage1_kernel  <<<6272, 256, 0, stream>>>(x, w1, g1, b1, m1, v1, p1bf);
    conv2m_kernel  <<<1024, 256, 0, stream>>>((const short*)p1bf, (const short*)w2s,
                                              sc2, b2, m2, a2t);
    stage2_kernel  <<<1568, 256, 0, stream>>>(a2t, p2bf);
    prep_fc1_kernel<<<3528, 256, 0, stream>>>(fc1w, w1s);    // overlays dead a2t
    fc1m_kernel    <<<dim3(8, 9, 7), 256, 0, stream>>>((const short*)p2bf, w1s, part);
    lif2_kernel    <<<288,  256, 0, stream>>>(part, s3bf);
    fc2tail_kernel <<<64,   256, 0, stream>>>((const short*)s3bf, fc2w, fc3w, out);
}